// Round 3
// baseline (136.461 us; speedup 1.0000x reference)
//
#include <hip/hip_runtime.h>

// ---------------------------------------------------------------------------
// Tree_42520176230890 (fused v3):
//   feats = x[:, using_idx]            (gather, bf16, natural layout)
//   d = sigmoid(feats @ W + b)         (bf16 MFMA; B streamed L2->regs,
//                                       A LDS dbuf BK=64, 16 barriers)
//   tree expansion in-block -> out (16384, 2048) f32, d never hits HBM
// ---------------------------------------------------------------------------

typedef __bf16 bf16x8 __attribute__((ext_vector_type(8)));
typedef float  f32x4  __attribute__((ext_vector_type(4)));

#define BATCH 16384
#define NLEAF 1024
#define FEAT  1024
#define OUTC  2048

__device__ __forceinline__ unsigned short f2bf(float f) {
    union { float f; unsigned int u; } c; c.f = f;
    unsigned int u = c.u;
    u += 0x7FFFu + ((u >> 16) & 1u);   // RNE
    return (unsigned short)(u >> 16);
}

__device__ __forceinline__ void load_lds16(const void* g, void* l) {
    __builtin_amdgcn_global_load_lds(
        (const __attribute__((address_space(1))) unsigned int*)g,
        (__attribute__((address_space(3))) unsigned int*)l, 16, 0, 0);
}

__device__ __forceinline__ float sigmoidf(float z) {
    return 1.0f / (1.0f + __expf(-z));
}

// --- 1. idx[l] = argmax_f feature_mask[f][l] -------------------------------
__global__ void extract_idx(const float* __restrict__ fm, int* __restrict__ idx) {
    int f = blockIdx.x;
    int t = threadIdx.x;
    if (fm[(size_t)f * NLEAF + t] > 0.5f) idx[t] = f;
}

// --- 2. Wt[n][k] = bf16(W[k][n]) (natural, B is read global->regs) ---------
__global__ __launch_bounds__(256) void transpose_w(const float* __restrict__ W,
                                                   short* __restrict__ Wt) {
    __shared__ short tile[64][65];
    int k0 = blockIdx.y * 64, n0 = blockIdx.x * 64;
#pragma unroll
    for (int i = 0; i < 16; ++i) {
        int e = i * 256 + threadIdx.x;
        int kr = e >> 6, nc = e & 63;
        tile[kr][nc] = (short)f2bf(W[(size_t)(k0 + kr) * NLEAF + n0 + nc]);
    }
    __syncthreads();
#pragma unroll
    for (int i = 0; i < 16; ++i) {
        int e = i * 256 + threadIdx.x;
        int nr = e >> 6, kc = e & 63;
        Wt[(size_t)(n0 + nr) * FEAT + k0 + kc] = tile[kc][nr];
    }
}

// --- 3. feats[r][k] = bf16(x[r][idx[k]]) (natural layout) ------------------
__global__ __launch_bounds__(256) void gather_feats(const float* __restrict__ x,
                                                    const int* __restrict__ idx,
                                                    short* __restrict__ feats) {
    int tid = blockIdx.x * 256 + threadIdx.x;   // BATCH*128 threads
    int r  = tid >> 7;
    int kk = (tid & 127) * 8;
    const float* xr = x + (size_t)r * FEAT;
    union { short s[8]; int4 v; } pk;
#pragma unroll
    for (int j = 0; j < 8; ++j) pk.s[j] = (short)f2bf(xr[idx[kk + j]]);
    *(int4*)(feats + (size_t)r * FEAT + kk) = pk.v;
}

// --- 4. fused GEMM + sigmoid + tree expansion ------------------------------
// block: 64 rows x N=1024, 512 thr (8 waves, wave-tile 64x128).
// A: LDS dbuf [2][64][64] bf16 (16 KiB), XOR-swizzled via pre-swizzled
//    global source addresses (global_load_lds writes linearly).
// B: global->registers (W bf16 = 2 MiB, L2-resident).
// Epilogue: 4 supergroups of 16 rows; dsm[16][1024] f32 (64 KiB, XOR swz).
__global__ __launch_bounds__(512, 2) void fused_gemm_tree(
        const short* __restrict__ feats, const short* __restrict__ Wt,
        const float* __restrict__ bias, float* __restrict__ out) {
    __shared__ __align__(16) char smem[65536];
    short* As = (short*)smem;                    // 2 bufs x 4096 shorts
    float (*dsm)[1024] = (float(*)[1024])smem;   // 16 x 1024 f32

    const int t  = threadIdx.x;
    const int l  = t & 63;
    const int w  = t >> 6;
    const int lr = l & 15, lk = l >> 4;
    const int row0 = blockIdx.x * 64;

    // A staging: thread t -> LDS slot16 t (linear); content = logical slot
    // (t&7)^((t>>3)&7) of row t>>3  (inverse-swizzled source, rule 21)
    const int arow = t >> 3;
    const int alog = (t & 7) ^ (arow & 7);
    const short* asrc = feats + (size_t)(row0 + arow) * FEAT + (alog << 3);

    // A ds_read offsets (shorts): row m*16+lr, logical slot c*4+lk,
    // physical slot = logical ^ (row&7) = logical ^ (lr&7)
    int aoff[2][4];
#pragma unroll
    for (int c = 0; c < 2; ++c)
#pragma unroll
        for (int m = 0; m < 4; ++m)
            aoff[c][m] = (m * 16 + lr) * 64 + ((((c << 2) + lk) ^ (lr & 7)) << 3);

    // B: per-lane base. frag (n, ksub c, step s):
    //   Wt[(w*128 + n*16 + lr)][s*64 + c*32 + lk*8]
    const short* bbase = Wt + (size_t)((w << 7) + lr) * FEAT + (lk << 3);

    float bvreg[8];
#pragma unroll
    for (int n = 0; n < 8; ++n) bvreg[n] = bias[(w << 7) + (n << 4) + lr];

    f32x4 acc[4][8];
#pragma unroll
    for (int m = 0; m < 4; ++m)
#pragma unroll
        for (int n = 0; n < 8; ++n)
#pragma unroll
            for (int r = 0; r < 4; ++r) acc[m][n][r] = 0.0f;

    load_lds16(asrc, As + t * 8);    // stage step 0 into buf 0
    __syncthreads();

    for (int s = 0; s < 16; ++s) {
        const int cur = s & 1;
        if (s < 15)
            load_lds16(asrc + (s + 1) * 64, As + (cur ^ 1) * 4096 + t * 8);

        const short* Ab = As + cur * 4096;
        const short* bs = bbase + s * 64;

        bf16x8 bv0[8], bv1[8], av0[4], av1[4];
#pragma unroll
        for (int n = 0; n < 8; ++n)
            bv0[n] = *(const bf16x8*)(bs + n * 16 * FEAT);
#pragma unroll
        for (int n = 0; n < 8; ++n)
            bv1[n] = *(const bf16x8*)(bs + n * 16 * FEAT + 32);
#pragma unroll
        for (int m = 0; m < 4; ++m) av0[m] = *(const bf16x8*)(Ab + aoff[0][m]);
#pragma unroll
        for (int m = 0; m < 4; ++m) av1[m] = *(const bf16x8*)(Ab + aoff[1][m]);

#pragma unroll
        for (int m = 0; m < 4; ++m)
#pragma unroll
            for (int n = 0; n < 8; ++n)
                acc[m][n] = __builtin_amdgcn_mfma_f32_16x16x32_bf16(
                    av0[m], bv0[n], acc[m][n], 0, 0, 0);
#pragma unroll
        for (int m = 0; m < 4; ++m)
#pragma unroll
            for (int n = 0; n < 8; ++n)
                acc[m][n] = __builtin_amdgcn_mfma_f32_16x16x32_bf16(
                    av1[m], bv1[n], acc[m][n], 0, 0, 0);
        __syncthreads();
    }

    // ---- epilogue: supergroup sg = fragment-row m covers rows sg*16..+16 --
#pragma unroll
    for (int sg = 0; sg < 4; ++sg) {
        if (sg) __syncthreads();          // prior sg's dsm reads done
        // dump d = sigmoid(acc + bias); dsm col XOR-swizzled by row
#pragma unroll
        for (int n = 0; n < 8; ++n) {
            const int col = (w << 7) + (n << 4) + lr;
#pragma unroll
            for (int rr = 0; rr < 4; ++rr) {
                const int row = (lk << 2) + rr;
                dsm[row][col ^ ((row & 7) << 2)] =
                    sigmoidf(acc[sg][n][rr] + bvreg[n]);
            }
        }
        __syncthreads();
        // expansion: wave w -> 2 rows
#pragma unroll
        for (int rh = 0; rh < 2; ++rh) {
            const int lrow = (w << 1) + rh;
            const int xr = (lrow & 7) << 2;
            const float* dr = dsm[lrow];
            float* orow = out + (size_t)(row0 + (sg << 4) + lrow) * OUTC;
#define D(j) dr[(j) ^ xr]
            // levels 0..5: lane l tracks its level-5 ancestor's path product
            float p = 1.0f;
#pragma unroll
            for (int j = 0; j <= 5; ++j) {
                int idx = l >> (5 - j);
                int node = (1 << j) + (idx >> 1);
                float dv = D(node);
                p *= (idx & 1) ? (1.0f - dv) : dv;
                if ((l & ((1 << (5 - j)) - 1)) == 0)
                    orow[(2 << j) + idx] = p;
            }
            if (l < 2) orow[l] = 1.0f;

            // L=6
            float d6 = D(64 + l);
            float v6[2] = { p * d6, p * (1.0f - d6) };
            *(float2*)(orow + 128 + 2 * l) = make_float2(v6[0], v6[1]);

            // L=7
            float d7[2] = { D(128 + 2 * l), D(129 + 2 * l) };
            float v7[4];
#pragma unroll
            for (int e = 0; e < 4; ++e)
                v7[e] = v6[e >> 1] * ((e & 1) ? (1.0f - d7[e >> 1]) : d7[e >> 1]);
            *(float4*)(orow + 256 + 4 * l) = make_float4(v7[0], v7[1], v7[2], v7[3]);

            // L=8
            float d8[4], v8[8];
#pragma unroll
            for (int q = 0; q < 4; ++q) d8[q] = D(256 + 4 * l + q);
#pragma unroll
            for (int e = 0; e < 8; ++e)
                v8[e] = v7[e >> 1] * ((e & 1) ? (1.0f - d8[e >> 1]) : d8[e >> 1]);
            *(float4*)(orow + 512 + 8 * l)     = make_float4(v8[0], v8[1], v8[2], v8[3]);
            *(float4*)(orow + 512 + 8 * l + 4) = make_float4(v8[4], v8[5], v8[6], v8[7]);

            // L=9
            float d9[8], v9[16];
#pragma unroll
            for (int q = 0; q < 8; ++q) d9[q] = D(512 + 8 * l + q);
#pragma unroll
            for (int e = 0; e < 16; ++e)
                v9[e] = v8[e >> 1] * ((e & 1) ? (1.0f - d9[e >> 1]) : d9[e >> 1]);
#pragma unroll
            for (int q = 0; q < 4; ++q)
                *(float4*)(orow + 1024 + 16 * l + 4 * q) =
                    make_float4(v9[4*q], v9[4*q+1], v9[4*q+2], v9[4*q+3]);
#undef D
        }
    }
}

// --- fallback (tiny workspace): naive fused, one row per block -------------
template <bool HAS_IDX>
__global__ __launch_bounds__(256) void fused_naive(const float* __restrict__ x,
                                                   const float* __restrict__ fm,
                                                   const float* __restrict__ W,
                                                   const float* __restrict__ bias,
                                                   const int* __restrict__ idx,
                                                   float* __restrict__ out) {
    __shared__ float fx[1024];
    __shared__ float dsm[1024];
    __shared__ float tre[2048];
    __shared__ int   idl[1024];
    const int t = threadIdx.x;
    const int row = blockIdx.x;

    if (HAS_IDX) {
        for (int k = t; k < 1024; k += 256) idl[k] = idx[k];
    } else {
        for (int k = t; k < 1024; k += 256) {
            int found = 0;
            for (int f = 0; f < 1024; ++f)
                if (fm[(size_t)f * NLEAF + k] > 0.5f) found = f;
            idl[k] = found;
        }
    }
    __syncthreads();
    const float* xr = x + (size_t)row * FEAT;
    for (int k = t; k < 1024; k += 256) fx[k] = xr[idl[k]];
    __syncthreads();

    float a0 = 0.f, a1 = 0.f, a2 = 0.f, a3 = 0.f;
    for (int k = 0; k < 1024; ++k) {
        float f = fx[k];
        const float* wrp = W + (size_t)k * NLEAF + t;
        a0 = fmaf(f, wrp[0],   a0);
        a1 = fmaf(f, wrp[256], a1);
        a2 = fmaf(f, wrp[512], a2);
        a3 = fmaf(f, wrp[768], a3);
    }
    dsm[t]       = sigmoidf(a0 + bias[t]);
    dsm[t + 256] = sigmoidf(a1 + bias[t + 256]);
    dsm[t + 512] = sigmoidf(a2 + bias[t + 512]);
    dsm[t + 768] = sigmoidf(a3 + bias[t + 768]);
    if (t < 2) tre[t] = 1.0f;
    __syncthreads();

    for (int L = 0; L < 10; ++L) {
        int n = 2 << L;
        for (int k = t; k < n; k += 256) {
            int node = (1 << L) + (k >> 1);
            float dv = dsm[node];
            tre[n + k] = tre[node] * ((k & 1) ? (1.0f - dv) : dv);
        }
        __syncthreads();
    }
    float4* orow = (float4*)(out + (size_t)row * OUTC);
    const float4* ts = (const float4*)tre;
    for (int i = t; i < 512; i += 256) orow[i] = ts[i];
}

extern "C" void kernel_launch(void* const* d_in, const int* in_sizes, int n_in,
                              void* d_out, int out_size, void* d_ws, size_t ws_size,
                              hipStream_t stream) {
    const float* x    = (const float*)d_in[0];
    const float* fm   = (const float*)d_in[1];
    const float* W    = (const float*)d_in[2];
    const float* bias = (const float*)d_in[3];
    float* out = (float*)d_out;

    const size_t IDX_B   = 4096;
    const size_t WT_B    = (size_t)NLEAF * FEAT * 2;        // 2 MiB
    const size_t FEATS_B = (size_t)BATCH * FEAT * 2;        // 32 MiB
    const size_t need = IDX_B + WT_B + FEATS_B;

    if (ws_size >= need) {
        int*   idx   = (int*)d_ws;
        short* Wt    = (short*)((char*)d_ws + IDX_B);
        short* feats = (short*)((char*)d_ws + IDX_B + WT_B);

        extract_idx<<<1024, 1024, 0, stream>>>(fm, idx);
        transpose_w<<<dim3(16, 16), 256, 0, stream>>>(W, Wt);
        gather_feats<<<BATCH * 128 / 256, 256, 0, stream>>>(x, idx, feats);
        fused_gemm_tree<<<BATCH / 64, 512, 0, stream>>>(feats, Wt, bias, out);
    } else if (ws_size >= IDX_B) {
        int* idx = (int*)d_ws;
        extract_idx<<<1024, 1024, 0, stream>>>(fm, idx);
        fused_naive<true><<<BATCH, 256, 0, stream>>>(x, fm, W, bias, idx, out);
    } else {
        fused_naive<false><<<BATCH, 256, 0, stream>>>(x, fm, W, bias, nullptr, out);
    }
}

// Round 6
// 132.103 us; speedup vs baseline: 1.0330x; 1.0330x over previous
//
#include <hip/hip_runtime.h>

// ---------------------------------------------------------------------------
// Tree_42520176230890 (fused v6):
//   feats = x[:, using_idx]      (gather, bf16, k-slot XOR-swizzled in memory)
//   d = sigmoid(feats @ W + b)   (bf16 MFMA; A full-K panel in chunk-major
//                                 LDS, staged in 4 chunks overlapped with
//                                 compute; B streamed L2->regs; 512 thr)
//   tree expansion in-block      (phi-skewed f32 dsm, conflict-free reads)
//   out: (16384, 2048) f32; d never touches HBM
// ---------------------------------------------------------------------------

typedef __bf16 bf16x8 __attribute__((ext_vector_type(8)));
typedef float  f32x4  __attribute__((ext_vector_type(4)));

#define BATCH 16384
#define NLEAF 1024
#define FEAT  1024
#define OUTC  2048
#define DSTRIDE 1153   // dsm row stride (f32): 1153 % 32 == 1

__device__ __forceinline__ unsigned short f2bf(float f) {
    union { float f; unsigned int u; } c; c.f = f;
    unsigned int u = c.u;
    u += 0x7FFFu + ((u >> 16) & 1u);   // RNE
    return (unsigned short)(u >> 16);
}

__device__ __forceinline__ void load_lds16(const void* g, void* l) {
    __builtin_amdgcn_global_load_lds(
        (const __attribute__((address_space(1))) unsigned int*)g,
        (__attribute__((address_space(3))) unsigned int*)l, 16, 0, 0);
}

__device__ __forceinline__ float sigmoidf(float z) {
    return 1.0f / (1.0f + __expf(-z));
}

// --- 1. idx[l] = argmax_f feature_mask[f][l] -------------------------------
__global__ void extract_idx(const float* __restrict__ fm, int* __restrict__ idx) {
    int f = blockIdx.x;
    int t = threadIdx.x;
    if (fm[(size_t)f * NLEAF + t] > 0.5f) idx[t] = f;
}

// --- 2. Wt[n][k] = bf16(W[k][n]) (natural layout; B read global->regs) -----
__global__ __launch_bounds__(256) void transpose_w(const float* __restrict__ W,
                                                   short* __restrict__ Wt) {
    __shared__ short tile[64][65];
    int k0 = blockIdx.y * 64, n0 = blockIdx.x * 64;
#pragma unroll
    for (int i = 0; i < 16; ++i) {
        int e = i * 256 + threadIdx.x;
        int kr = e >> 6, nc = e & 63;
        tile[kr][nc] = (short)f2bf(W[(size_t)(k0 + kr) * NLEAF + n0 + nc]);
    }
    __syncthreads();
#pragma unroll
    for (int i = 0; i < 16; ++i) {
        int e = i * 256 + threadIdx.x;
        int nr = e >> 6, kc = e & 63;
        Wt[(size_t)(n0 + nr) * FEAT + k0 + kc] = tile[kc][nr];
    }
}

// --- 3. feats[r][slot^(r&7)] = bf16(x[r][idx[slot*8+j]]) -------------------
// 16B-slot XOR swizzle by row (validated in v2); fused kernel stages chunks
// linearly and XORs the ds_read slot (low 3 bits only) -> conflict-free.
__global__ __launch_bounds__(256) void gather_feats(const float* __restrict__ x,
                                                    const int* __restrict__ idx,
                                                    short* __restrict__ feats) {
    int tid = blockIdx.x * 256 + threadIdx.x;   // BATCH*128 threads
    int r    = tid >> 7;
    int slot = tid & 127;
    const float* xr = x + (size_t)r * FEAT;
    union { short s[8]; int4 v; } pk;
#pragma unroll
    for (int j = 0; j < 8; ++j) pk.s[j] = (short)f2bf(xr[idx[slot * 8 + j]]);
    *(int4*)(feats + (size_t)r * FEAT + ((slot ^ (r & 7)) << 3)) = pk.v;
}

// --- 4. fused GEMM + sigmoid + tree expansion ------------------------------
// 512 thr (8 waves), block = 64 rows x 1024 cols, wave-tile 64x128.
// A: 128 KiB LDS, CHUNK-MAJOR [4][64 rows][32 slot16] so each chunk stage is
//    wave-uniform-base + lane*16 (global_load_lds rule). Stage c+1 under
//    compute of chunk c -> 4 K-loop barriers. B: global->regs from L2-hot Wt.
// Epilogue: 4 supergroups x 16 rows; dsm f32 [16][1153], phi(j)=j+(j>>3).
__global__ __launch_bounds__(512, 2) void fused_gemm_tree(
        const short* __restrict__ feats, const short* __restrict__ Wt,
        const float* __restrict__ bias, float* __restrict__ out) {
    __shared__ __align__(16) char smem[131072];
    short* As  = (short*)smem;        // [4][64][32] slot16 (chunk-major)
    float* dsm = (float*)smem;        // [16][DSTRIDE] f32 (73792 B)

    const int t  = threadIdx.x;
    const int l  = t & 63;
    const int w  = t >> 6;            // 0..7 : col group (128 cols)
    const int lr = l & 15, lk = l >> 4;
    const int row0 = blockIdx.x * 64;

    float bvreg[8];
#pragma unroll
    for (int n = 0; n < 8; ++n) bvreg[n] = bias[(w << 7) + (n << 4) + lr];

    // A ds_read byte offsets within a chunk: row m*16+lr (stride 512 B),
    // slot (cc*4+lk)^(lr&7); add c*32768 + sl*128 at use site.
    int aoff[2][4];
#pragma unroll
    for (int cc = 0; cc < 2; ++cc)
#pragma unroll
        for (int m = 0; m < 4; ++m)
            aoff[cc][m] = (m * 16 + lr) * 512
                        + ((((cc << 2) + lk) ^ (lr & 7)) << 4);

    // B per-lane bases: col = w*128 + n*16 + lr, k-slot lk; steps via offsets
    const short* bptr[8];
#pragma unroll
    for (int n = 0; n < 8; ++n)
        bptr[n] = Wt + (size_t)((w << 7) + (n << 4) + lr) * FEAT + (lk << 3);

    // Stage chunk c (k range [c*256, c*256+256)): 2048 slot16s, contiguous in
    // LDS at [c*2048 .. c*2048+2048). Slot = c*2048 + j*512 + w*64 + lane
    // -> wave-uniform base + lane*16. Global src per-lane (allowed).
    auto stageA = [&](int c) {
#pragma unroll
        for (int j = 0; j < 4; ++j) {
            int idx = j * 512 + t;            // 0..2047
            int row = idx >> 5, q = idx & 31; // feats phys slot c*32+q
            load_lds16(feats + (size_t)(row0 + row) * FEAT + (((c << 5) + q) << 3),
                       As + (((c << 11) + idx) << 3));
        }
    };

    f32x4 acc[4][8];
#pragma unroll
    for (int m = 0; m < 4; ++m)
#pragma unroll
        for (int n = 0; n < 8; ++n)
#pragma unroll
            for (int r = 0; r < 4; ++r) acc[m][n][r] = 0.0f;

    stageA(0);
    __syncthreads();

    // ---- K-loop: 4 chunks x 4 steps (BK=64); stage c+1 under compute c ----
#pragma unroll
    for (int c = 0; c < 4; ++c) {
        if (c < 3) stageA(c + 1);
        const char* Ac = (const char*)As + c * 32768;
#pragma unroll
        for (int sl = 0; sl < 4; ++sl) {
            const int S = (c << 2) + sl;
#pragma unroll
            for (int cc = 0; cc < 2; ++cc) {
                bf16x8 av[4], bv[8];
#pragma unroll
                for (int n = 0; n < 8; ++n)
                    bv[n] = *(const bf16x8*)(bptr[n] + S * 64 + cc * 32);
#pragma unroll
                for (int m = 0; m < 4; ++m)
                    av[m] = *(const bf16x8*)(Ac + aoff[cc][m] + sl * 128);
#pragma unroll
                for (int m = 0; m < 4; ++m)
#pragma unroll
                    for (int n = 0; n < 8; ++n)
                        acc[m][n] = __builtin_amdgcn_mfma_f32_16x16x32_bf16(
                            av[m], bv[n], acc[m][n], 0, 0, 0);
            }
        }
        __syncthreads();   // chunk c reads done everywhere; chunk c+1 staged
    }

    // ---- epilogue: 4 supergroups of 16 rows (sg = fragment-row m) ---------
#pragma unroll
    for (int sg = 0; sg < 4; ++sg) {
        if (sg) __syncthreads();      // prior sg's dsm reads done
        // dump d = sigmoid(acc + bias) into phi-skewed dsm
#pragma unroll
        for (int n = 0; n < 8; ++n) {
            const int col = (w << 7) + (n << 4) + lr;
            const int ph  = col + (col >> 3);
#pragma unroll
            for (int rr = 0; rr < 4; ++rr) {
                const int rloc = (lk << 2) + rr;
                dsm[rloc * DSTRIDE + ph] = sigmoidf(acc[sg][n][rr] + bvreg[n]);
            }
        }
        __syncthreads();
        // expansion: wave w -> rows w*2, w*2+1 of this supergroup
#pragma unroll
        for (int rh = 0; rh < 2; ++rh) {
            const int rloc = (w << 1) + rh;
            const float* dr = dsm + rloc * DSTRIDE;
            float* orow = out + (size_t)(row0 + (sg << 4) + rloc) * OUTC;
#define D(j) dr[(j) + ((j) >> 3)]
            // levels 0..5: lane l tracks its level-5 ancestor's path product
            float p = 1.0f;
#pragma unroll
            for (int j = 0; j <= 5; ++j) {
                int idx = l >> (5 - j);
                int node = (1 << j) + (idx >> 1);
                float dv = D(node);
                p *= (idx & 1) ? (1.0f - dv) : dv;
                if ((l & ((1 << (5 - j)) - 1)) == 0)
                    orow[(2 << j) + idx] = p;
            }
            if (l < 2) orow[l] = 1.0f;

            // L=6
            float d6 = D(64 + l);
            float v6[2] = { p * d6, p * (1.0f - d6) };
            *(float2*)(orow + 128 + 2 * l) = make_float2(v6[0], v6[1]);

            // L=7
            float d7[2] = { D(128 + 2 * l), D(129 + 2 * l) };
            float v7[4];
#pragma unroll
            for (int e = 0; e < 4; ++e)
                v7[e] = v6[e >> 1] * ((e & 1) ? (1.0f - d7[e >> 1]) : d7[e >> 1]);
            *(float4*)(orow + 256 + 4 * l) = make_float4(v7[0], v7[1], v7[2], v7[3]);

            // L=8
            float d8[4], v8[8];
#pragma unroll
            for (int q = 0; q < 4; ++q) d8[q] = D(256 + 4 * l + q);
#pragma unroll
            for (int e = 0; e < 8; ++e)
                v8[e] = v7[e >> 1] * ((e & 1) ? (1.0f - d8[e >> 1]) : d8[e >> 1]);
            *(float4*)(orow + 512 + 8 * l)     = make_float4(v8[0], v8[1], v8[2], v8[3]);
            *(float4*)(orow + 512 + 8 * l + 4) = make_float4(v8[4], v8[5], v8[6], v8[7]);

            // L=9
            float d9[8], v9[16];
#pragma unroll
            for (int q = 0; q < 8; ++q) d9[q] = D(512 + 8 * l + q);
#pragma unroll
            for (int e = 0; e < 16; ++e)
                v9[e] = v8[e >> 1] * ((e & 1) ? (1.0f - d9[e >> 1]) : d9[e >> 1]);
#pragma unroll
            for (int q = 0; q < 4; ++q)
                *(float4*)(orow + 1024 + 16 * l + 4 * q) =
                    make_float4(v9[4*q], v9[4*q+1], v9[4*q+2], v9[4*q+3]);
#undef D
        }
    }
}

// --- fallback (tiny workspace): naive fused, one row per block -------------
template <bool HAS_IDX>
__global__ __launch_bounds__(256) void fused_naive(const float* __restrict__ x,
                                                   const float* __restrict__ fm,
                                                   const float* __restrict__ W,
                                                   const float* __restrict__ bias,
                                                   const int* __restrict__ idx,
                                                   float* __restrict__ out) {
    __shared__ float fx[1024];
    __shared__ float dsm[1024];
    __shared__ float tre[2048];
    __shared__ int   idl[1024];
    const int t = threadIdx.x;
    const int row = blockIdx.x;

    if (HAS_IDX) {
        for (int k = t; k < 1024; k += 256) idl[k] = idx[k];
    } else {
        for (int k = t; k < 1024; k += 256) {
            int found = 0;
            for (int f = 0; f < 1024; ++f)
                if (fm[(size_t)f * NLEAF + k] > 0.5f) found = f;
            idl[k] = found;
        }
    }
    __syncthreads();
    const float* xr = x + (size_t)row * FEAT;
    for (int k = t; k < 1024; k += 256) fx[k] = xr[idl[k]];
    __syncthreads();

    float a0 = 0.f, a1 = 0.f, a2 = 0.f, a3 = 0.f;
    for (int k = 0; k < 1024; ++k) {
        float f = fx[k];
        const float* wrp = W + (size_t)k * NLEAF + t;
        a0 = fmaf(f, wrp[0],   a0);
        a1 = fmaf(f, wrp[256], a1);
        a2 = fmaf(f, wrp[512], a2);
        a3 = fmaf(f, wrp[768], a3);
    }
    dsm[t]       = sigmoidf(a0 + bias[t]);
    dsm[t + 256] = sigmoidf(a1 + bias[t + 256]);
    dsm[t + 512] = sigmoidf(a2 + bias[t + 512]);
    dsm[t + 768] = sigmoidf(a3 + bias[t + 768]);
    if (t < 2) tre[t] = 1.0f;
    __syncthreads();

    for (int L = 0; L < 10; ++L) {
        int n = 2 << L;
        for (int k = t; k < n; k += 256) {
            int node = (1 << L) + (k >> 1);
            float dv = dsm[node];
            tre[n + k] = tre[node] * ((k & 1) ? (1.0f - dv) : dv);
        }
        __syncthreads();
    }
    float4* orow = (float4*)(out + (size_t)row * OUTC);
    const float4* ts = (const float4*)tre;
    for (int i = t; i < 512; i += 256) orow[i] = ts[i];
}

extern "C" void kernel_launch(void* const* d_in, const int* in_sizes, int n_in,
                              void* d_out, int out_size, void* d_ws, size_t ws_size,
                              hipStream_t stream) {
    const float* x    = (const float*)d_in[0];
    const float* fm   = (const float*)d_in[1];
    const float* W    = (const float*)d_in[2];
    const float* bias = (const float*)d_in[3];
    float* out = (float*)d_out;

    const size_t IDX_B   = 4096;
    const size_t WT_B    = (size_t)NLEAF * FEAT * 2;        // 2 MiB
    const size_t FEATS_B = (size_t)BATCH * FEAT * 2;        // 32 MiB
    const size_t need = IDX_B + WT_B + FEATS_B;

    if (ws_size >= need) {
        int*   idx   = (int*)d_ws;
        short* Wt    = (short*)((char*)d_ws + IDX_B);
        short* feats = (short*)((char*)d_ws + IDX_B + WT_B);

        extract_idx<<<1024, 1024, 0, stream>>>(fm, idx);
        transpose_w<<<dim3(16, 16), 256, 0, stream>>>(W, Wt);
        gather_feats<<<BATCH * 128 / 256, 256, 0, stream>>>(x, idx, feats);
        fused_gemm_tree<<<BATCH / 64, 512, 0, stream>>>(feats, Wt, bias, out);
    } else if (ws_size >= IDX_B) {
        int* idx = (int*)d_ws;
        extract_idx<<<1024, 1024, 0, stream>>>(fm, idx);
        fused_naive<true><<<BATCH, 256, 0, stream>>>(x, fm, W, bias, idx, out);
    } else {
        fused_naive<false><<<BATCH, 256, 0, stream>>>(x, fm, W, bias, nullptr, out);
    }
}

// Round 7
// 131.312 us; speedup vs baseline: 1.0392x; 1.0060x over previous
//
#include <hip/hip_runtime.h>

// ---------------------------------------------------------------------------
// Tree_42520176230890 (fused v7):
//   feats = x[:, using_idx]      (gather, bf16, NATURAL layout)
//   d = sigmoid(feats @ W + b)   (bf16 MFMA; B LDS-dbuf staged via
//                                 global_load_lds, A global->reg L1-hot;
//                                 1 barrier/chunk, 32 chunks of BK=32)
//   tree expansion in-block      (phi-skewed f32 dsm)
//   out: (16384, 2048) f32; d never touches HBM
// ---------------------------------------------------------------------------

typedef __bf16 bf16x8 __attribute__((ext_vector_type(8)));
typedef float  f32x4  __attribute__((ext_vector_type(4)));

#define BATCH 16384
#define NLEAF 1024
#define FEAT  1024
#define OUTC  2048
#define DSTRIDE 1153   // dsm row stride (f32): 1153 % 32 == 1

__device__ __forceinline__ unsigned short f2bf(float f) {
    union { float f; unsigned int u; } c; c.f = f;
    unsigned int u = c.u;
    u += 0x7FFFu + ((u >> 16) & 1u);   // RNE
    return (unsigned short)(u >> 16);
}

__device__ __forceinline__ void load_lds16(const void* g, void* l) {
    __builtin_amdgcn_global_load_lds(
        (const __attribute__((address_space(1))) unsigned int*)g,
        (__attribute__((address_space(3))) unsigned int*)l, 16, 0, 0);
}

__device__ __forceinline__ float sigmoidf(float z) {
    return 1.0f / (1.0f + __expf(-z));
}

// --- 1. idx[l] = argmax_f feature_mask[f][l] -------------------------------
__global__ void extract_idx(const float* __restrict__ fm, int* __restrict__ idx) {
    int f = blockIdx.x;
    int t = threadIdx.x;
    if (fm[(size_t)f * NLEAF + t] > 0.5f) idx[t] = f;
}

// --- 2. Wt[n][k] = bf16(W[k][n]) (natural layout) --------------------------
__global__ __launch_bounds__(256) void transpose_w(const float* __restrict__ W,
                                                   short* __restrict__ Wt) {
    __shared__ short tile[64][65];
    int k0 = blockIdx.y * 64, n0 = blockIdx.x * 64;
#pragma unroll
    for (int i = 0; i < 16; ++i) {
        int e = i * 256 + threadIdx.x;
        int kr = e >> 6, nc = e & 63;
        tile[kr][nc] = (short)f2bf(W[(size_t)(k0 + kr) * NLEAF + n0 + nc]);
    }
    __syncthreads();
#pragma unroll
    for (int i = 0; i < 16; ++i) {
        int e = i * 256 + threadIdx.x;
        int nr = e >> 6, kc = e & 63;
        Wt[(size_t)(n0 + nr) * FEAT + k0 + kc] = tile[kc][nr];
    }
}

// --- 3. feats[r][k] = bf16(x[r][idx[k]])  (NATURAL layout) -----------------
__global__ __launch_bounds__(256) void gather_feats(const float* __restrict__ x,
                                                    const int* __restrict__ idx,
                                                    short* __restrict__ feats) {
    int tid = blockIdx.x * 256 + threadIdx.x;   // BATCH*128 threads
    int r  = tid >> 7;
    int kk = (tid & 127) * 8;
    const float* xr = x + (size_t)r * FEAT;
    union { short s[8]; int4 v; } pk;
#pragma unroll
    for (int j = 0; j < 8; ++j) pk.s[j] = (short)f2bf(xr[idx[kk + j]]);
    *(int4*)(feats + (size_t)r * FEAT + kk) = pk.v;
}

// --- 4. fused GEMM + sigmoid + tree expansion ------------------------------
// 512 thr (8 waves), block = 64 rows x 1024 cols, wave-tile 64x128.
// B: LDS dbuf [2][1024 cols][4 slot16] = 128 KiB, staged via global_load_lds
//    with source-side XOR (phys slot = srcslot ^ ((col>>1)&3)) so ds_read_b128
//    is <=2-way bank aliased (free). A: global->reg, 4 KiB/chunk shared by
//    all 8 waves -> L1-hot. 32 chunks of BK=32, ONE barrier per chunk.
// Epilogue: 4 supergroups x 16 rows; dsm f32 [16][1153], phi(j)=j+(j>>3).
__global__ __launch_bounds__(512, 2) void fused_gemm_tree(
        const short* __restrict__ feats, const short* __restrict__ Wt,
        const float* __restrict__ bias, float* __restrict__ out) {
    __shared__ __align__(16) char smem[131072];
    short* Bs  = (short*)smem;        // [2][4096] slot16 (col*4 + physslot)
    float* dsm = (float*)smem;        // [16][DSTRIDE] f32 (73792 B)

    const int t  = threadIdx.x;
    const int l  = t & 63;
    const int w  = t >> 6;            // 0..7 : col group (128 cols)
    const int lr = l & 15, lk = l >> 4;
    const int row0 = blockIdx.x * 64;

    float bvreg[8];
#pragma unroll
    for (int n = 0; n < 8; ++n) bvreg[n] = bias[(w << 7) + (n << 4) + lr];

    // B ds_read byte offsets (within one buffer): col = w*128+n*16+lr,
    // phys slot = lk ^ ((lr>>1)&3)  (col's other bits are 0 mod 8 in >>1&3)
    int boff[8];
#pragma unroll
    for (int n = 0; n < 8; ++n) {
        int col = (w << 7) + (n << 4) + lr;
        int ps  = lk ^ ((lr >> 1) & 3);
        boff[n] = (col * 4 + ps) * 16;            // bytes
    }

    // A global bases: row = m*16 + lr, k-slot lk (advance by ch*64 bytes)
    const short* aptr[4];
#pragma unroll
    for (int m = 0; m < 4; ++m)
        aptr[m] = feats + (size_t)(row0 + (m << 4) + lr) * FEAT + (lk << 3);

    // B staging for chunk ch into buffer buf: 4096 slot16s, 8 per thread.
    // slotidx = j*512 + t -> col = slotidx>>2, ps = slotidx&3,
    // src k-slot = ps ^ ((col>>1)&3). LDS dest = linear slot16 (wave-uniform
    // base + lane*16: slotidx = j*512 + w*64 + lane ✓).
    auto stageB = [&](int ch, int buf) {
#pragma unroll
        for (int j = 0; j < 8; ++j) {
            int slotidx = j * 512 + t;
            int col = slotidx >> 2, ps = slotidx & 3;
            int srcslot = ps ^ ((col >> 1) & 3);
            load_lds16(Wt + (size_t)col * FEAT + (ch << 5) + (srcslot << 3),
                       Bs + ((buf << 12) + slotidx) * 8);
        }
    };

    f32x4 acc[4][8];
#pragma unroll
    for (int m = 0; m < 4; ++m)
#pragma unroll
        for (int n = 0; n < 8; ++n)
#pragma unroll
            for (int r = 0; r < 4; ++r) acc[m][n][r] = 0.0f;

    stageB(0, 0);
    __syncthreads();

    // ---- K-loop: 32 chunks of BK=32; explicit parity (static buf index) ---
    for (int ch2 = 0; ch2 < 16; ++ch2) {
        // even chunk: compute buf 0, stage ch+1 into buf 1
        {
            const int ch = ch2 * 2;
            if (ch < 31) stageB(ch + 1, 1);
            bf16x8 av[4], bv[8];
#pragma unroll
            for (int m = 0; m < 4; ++m)
                av[m] = *(const bf16x8*)(aptr[m] + (ch << 5));
#pragma unroll
            for (int n = 0; n < 8; ++n)
                bv[n] = *(const bf16x8*)((const char*)Bs + boff[n]);
#pragma unroll
            for (int m = 0; m < 4; ++m)
#pragma unroll
                for (int n = 0; n < 8; ++n)
                    acc[m][n] = __builtin_amdgcn_mfma_f32_16x16x32_bf16(
                        av[m], bv[n], acc[m][n], 0, 0, 0);
            __syncthreads();
        }
        // odd chunk: compute buf 1, stage ch+1 into buf 0
        {
            const int ch = ch2 * 2 + 1;
            if (ch < 31) stageB(ch + 1, 0);
            bf16x8 av[4], bv[8];
#pragma unroll
            for (int m = 0; m < 4; ++m)
                av[m] = *(const bf16x8*)(aptr[m] + (ch << 5));
#pragma unroll
            for (int n = 0; n < 8; ++n)
                bv[n] = *(const bf16x8*)((const char*)Bs + 65536 + boff[n]);
#pragma unroll
            for (int m = 0; m < 4; ++m)
#pragma unroll
                for (int n = 0; n < 8; ++n)
                    acc[m][n] = __builtin_amdgcn_mfma_f32_16x16x32_bf16(
                        av[m], bv[n], acc[m][n], 0, 0, 0);
            __syncthreads();
        }
    }

    // ---- epilogue: 4 supergroups of 16 rows (sg = fragment-row m) ---------
#pragma unroll
    for (int sg = 0; sg < 4; ++sg) {
        if (sg) __syncthreads();      // prior sg's dsm reads done
        // dump d = sigmoid(acc + bias) into phi-skewed dsm
#pragma unroll
        for (int n = 0; n < 8; ++n) {
            const int col = (w << 7) + (n << 4) + lr;
            const int ph  = col + (col >> 3);
#pragma unroll
            for (int rr = 0; rr < 4; ++rr) {
                const int rloc = (lk << 2) + rr;
                dsm[rloc * DSTRIDE + ph] = sigmoidf(acc[sg][n][rr] + bvreg[n]);
            }
        }
        __syncthreads();
        // expansion: wave w -> rows w*2, w*2+1 of this supergroup
#pragma unroll
        for (int rh = 0; rh < 2; ++rh) {
            const int rloc = (w << 1) + rh;
            const float* dr = dsm + rloc * DSTRIDE;
            float* orow = out + (size_t)(row0 + (sg << 4) + rloc) * OUTC;
#define D(j) dr[(j) + ((j) >> 3)]
            // levels 0..5: lane l tracks its level-5 ancestor's path product
            float p = 1.0f;
#pragma unroll
            for (int j = 0; j <= 5; ++j) {
                int idx = l >> (5 - j);
                int node = (1 << j) + (idx >> 1);
                float dv = D(node);
                p *= (idx & 1) ? (1.0f - dv) : dv;
                if ((l & ((1 << (5 - j)) - 1)) == 0)
                    orow[(2 << j) + idx] = p;
            }
            if (l < 2) orow[l] = 1.0f;

            // L=6
            float d6 = D(64 + l);
            float v6[2] = { p * d6, p * (1.0f - d6) };
            *(float2*)(orow + 128 + 2 * l) = make_float2(v6[0], v6[1]);

            // L=7
            float d7[2] = { D(128 + 2 * l), D(129 + 2 * l) };
            float v7[4];
#pragma unroll
            for (int e = 0; e < 4; ++e)
                v7[e] = v6[e >> 1] * ((e & 1) ? (1.0f - d7[e >> 1]) : d7[e >> 1]);
            *(float4*)(orow + 256 + 4 * l) = make_float4(v7[0], v7[1], v7[2], v7[3]);

            // L=8
            float d8[4], v8[8];
#pragma unroll
            for (int q = 0; q < 4; ++q) d8[q] = D(256 + 4 * l + q);
#pragma unroll
            for (int e = 0; e < 8; ++e)
                v8[e] = v7[e >> 1] * ((e & 1) ? (1.0f - d8[e >> 1]) : d8[e >> 1]);
            *(float4*)(orow + 512 + 8 * l)     = make_float4(v8[0], v8[1], v8[2], v8[3]);
            *(float4*)(orow + 512 + 8 * l + 4) = make_float4(v8[4], v8[5], v8[6], v8[7]);

            // L=9
            float d9[8], v9[16];
#pragma unroll
            for (int q = 0; q < 8; ++q) d9[q] = D(512 + 8 * l + q);
#pragma unroll
            for (int e = 0; e < 16; ++e)
                v9[e] = v8[e >> 1] * ((e & 1) ? (1.0f - d9[e >> 1]) : d9[e >> 1]);
#pragma unroll
            for (int q = 0; q < 4; ++q)
                *(float4*)(orow + 1024 + 16 * l + 4 * q) =
                    make_float4(v9[4*q], v9[4*q+1], v9[4*q+2], v9[4*q+3]);
#undef D
        }
    }
}

// --- fallback (tiny workspace): naive fused, one row per block -------------
template <bool HAS_IDX>
__global__ __launch_bounds__(256) void fused_naive(const float* __restrict__ x,
                                                   const float* __restrict__ fm,
                                                   const float* __restrict__ W,
                                                   const float* __restrict__ bias,
                                                   const int* __restrict__ idx,
                                                   float* __restrict__ out) {
    __shared__ float fx[1024];
    __shared__ float dsm[1024];
    __shared__ float tre[2048];
    __shared__ int   idl[1024];
    const int t = threadIdx.x;
    const int row = blockIdx.x;

    if (HAS_IDX) {
        for (int k = t; k < 1024; k += 256) idl[k] = idx[k];
    } else {
        for (int k = t; k < 1024; k += 256) {
            int found = 0;
            for (int f = 0; f < 1024; ++f)
                if (fm[(size_t)f * NLEAF + k] > 0.5f) found = f;
            idl[k] = found;
        }
    }
    __syncthreads();
    const float* xr = x + (size_t)row * FEAT;
    for (int k = t; k < 1024; k += 256) fx[k] = xr[idl[k]];
    __syncthreads();

    float a0 = 0.f, a1 = 0.f, a2 = 0.f, a3 = 0.f;
    for (int k = 0; k < 1024; ++k) {
        float f = fx[k];
        const float* wrp = W + (size_t)k * NLEAF + t;
        a0 = fmaf(f, wrp[0],   a0);
        a1 = fmaf(f, wrp[256], a1);
        a2 = fmaf(f, wrp[512], a2);
        a3 = fmaf(f, wrp[768], a3);
    }
    dsm[t]       = sigmoidf(a0 + bias[t]);
    dsm[t + 256] = sigmoidf(a1 + bias[t + 256]);
    dsm[t + 512] = sigmoidf(a2 + bias[t + 512]);
    dsm[t + 768] = sigmoidf(a3 + bias[t + 768]);
    if (t < 2) tre[t] = 1.0f;
    __syncthreads();

    for (int L = 0; L < 10; ++L) {
        int n = 2 << L;
        for (int k = t; k < n; k += 256) {
            int node = (1 << L) + (k >> 1);
            float dv = dsm[node];
            tre[n + k] = tre[node] * ((k & 1) ? (1.0f - dv) : dv);
        }
        __syncthreads();
    }
    float4* orow = (float4*)(out + (size_t)row * OUTC);
    const float4* ts = (const float4*)tre;
    for (int i = t; i < 512; i += 256) orow[i] = ts[i];
}

extern "C" void kernel_launch(void* const* d_in, const int* in_sizes, int n_in,
                              void* d_out, int out_size, void* d_ws, size_t ws_size,
                              hipStream_t stream) {
    const float* x    = (const float*)d_in[0];
    const float* fm   = (const float*)d_in[1];
    const float* W    = (const float*)d_in[2];
    const float* bias = (const float*)d_in[3];
    float* out = (float*)d_out;

    const size_t IDX_B   = 4096;
    const size_t WT_B    = (size_t)NLEAF * FEAT * 2;        // 2 MiB
    const size_t FEATS_B = (size_t)BATCH * FEAT * 2;        // 32 MiB
    const size_t need = IDX_B + WT_B + FEATS_B;

    if (ws_size >= need) {
        int*   idx   = (int*)d_ws;
        short* Wt    = (short*)((char*)d_ws + IDX_B);
        short* feats = (short*)((char*)d_ws + IDX_B + WT_B);

        extract_idx<<<1024, 1024, 0, stream>>>(fm, idx);
        transpose_w<<<dim3(16, 16), 256, 0, stream>>>(W, Wt);
        gather_feats<<<BATCH * 128 / 256, 256, 0, stream>>>(x, idx, feats);
        fused_gemm_tree<<<BATCH / 64, 512, 0, stream>>>(feats, Wt, bias, out);
    } else if (ws_size >= IDX_B) {
        int* idx = (int*)d_ws;
        extract_idx<<<1024, 1024, 0, stream>>>(fm, idx);
        fused_naive<true><<<BATCH, 256, 0, stream>>>(x, fm, W, bias, idx, out);
    } else {
        fused_naive<false><<<BATCH, 256, 0, stream>>>(x, fm, W, bias, nullptr, out);
    }
}

// Round 8
// 116.073 us; speedup vs baseline: 1.1756x; 1.1313x over previous
//
#include <hip/hip_runtime.h>

// ---------------------------------------------------------------------------
// Tree_42520176230890 (v8, un-fused):
//   feats = x[:, using_idx]            (gather, bf16, natural layout)
//   d = sigmoid(feats @ W + b)         (m97-structure GEMM: 128x128 tile,
//                                       256 thr, BK=32 dbuf LDS, 4 blk/CU;
//                                       d stored bf16 in out cols[1536:2048))
//   tree expansion                     (1 row/wave, register-only, 16 blk/CU)
//   out: (16384, 2048) f32
// ---------------------------------------------------------------------------

typedef __bf16 bf16x8 __attribute__((ext_vector_type(8)));
typedef float  f32x4  __attribute__((ext_vector_type(4)));

#define BATCH 16384
#define NLEAF 1024
#define FEAT  1024
#define OUTC  2048

__device__ __forceinline__ unsigned short f2bf(float f) {
    union { float f; unsigned int u; } c; c.f = f;
    unsigned int u = c.u;
    u += 0x7FFFu + ((u >> 16) & 1u);   // RNE
    return (unsigned short)(u >> 16);
}

__device__ __forceinline__ float bf2f(unsigned short u) {
    union { unsigned int i; float f; } c; c.i = (unsigned int)u << 16;
    return c.f;
}

__device__ __forceinline__ void load_lds16(const void* g, void* l) {
    __builtin_amdgcn_global_load_lds(
        (const __attribute__((address_space(1))) unsigned int*)g,
        (__attribute__((address_space(3))) unsigned int*)l, 16, 0, 0);
}

__device__ __forceinline__ float sigmoidf(float z) {
    return 1.0f / (1.0f + __expf(-z));
}

// --- 1. idx[l] = argmax_f feature_mask[f][l] -------------------------------
__global__ void extract_idx(const float* __restrict__ fm, int* __restrict__ idx) {
    int f = blockIdx.x;
    int t = threadIdx.x;
    if (fm[(size_t)f * NLEAF + t] > 0.5f) idx[t] = f;
}

// --- 2. Wt[n][k] = bf16(W[k][n]) (natural layout) --------------------------
__global__ __launch_bounds__(256) void transpose_w(const float* __restrict__ W,
                                                   short* __restrict__ Wt) {
    __shared__ short tile[64][65];
    int k0 = blockIdx.y * 64, n0 = blockIdx.x * 64;
#pragma unroll
    for (int i = 0; i < 16; ++i) {
        int e = i * 256 + threadIdx.x;
        int kr = e >> 6, nc = e & 63;
        tile[kr][nc] = (short)f2bf(W[(size_t)(k0 + kr) * NLEAF + n0 + nc]);
    }
    __syncthreads();
#pragma unroll
    for (int i = 0; i < 16; ++i) {
        int e = i * 256 + threadIdx.x;
        int nr = e >> 6, kc = e & 63;
        Wt[(size_t)(n0 + nr) * FEAT + k0 + kc] = tile[kc][nr];
    }
}

// --- 3. feats[r][k] = bf16(x[r][idx[k]])  (natural layout) -----------------
__global__ __launch_bounds__(256) void gather_feats(const float* __restrict__ x,
                                                    const int* __restrict__ idx,
                                                    short* __restrict__ feats) {
    int tid = blockIdx.x * 256 + threadIdx.x;   // BATCH*128 threads
    int r  = tid >> 7;
    int kk = (tid & 127) * 8;
    const float* xr = x + (size_t)r * FEAT;
    union { short s[8]; int4 v; } pk;
#pragma unroll
    for (int j = 0; j < 8; ++j) pk.s[j] = (short)f2bf(xr[idx[kk + j]]);
    *(int4*)(feats + (size_t)r * FEAT + kk) = pk.v;
}

// --- 4. GEMM + sigmoid -> d (bf16) into out byte-cols [3072:4096) ----------
// m97 structure: 128x128 tile, 256 thr (4 waves, 2x2), BK=32 dbuf (32 KiB),
// global_load_lds staging with src-side XOR sw(r)=(r^(r>>2))&3 -> ds_read
// conflict-free. Grid 1024 (= 4 blocks/CU). 1 barrier per chunk.
__global__ __launch_bounds__(256, 4) void gemm_sig_d(
        const short* __restrict__ feats, const short* __restrict__ Wt,
        const float* __restrict__ bias, unsigned short* __restrict__ dout) {
    __shared__ __align__(16) short As[2][128 * 32];
    __shared__ __align__(16) short Bs[2][128 * 32];

    const int t = threadIdx.x, l = t & 63, w = t >> 6;
    const int wr = w >> 1, wc = w & 1;
    const int lr = l & 15, lk = l >> 4;
    const int row0 = (blockIdx.x >> 3) << 7;   // 128 M-tiles
    const int n0   = (blockIdx.x & 7) << 7;    // 8 N-tiles

    float bvreg[4];
#pragma unroll
    for (int n = 0; n < 4; ++n) bvreg[n] = bias[n0 + wc * 64 + n * 16 + lr];

    // ds_read byte offsets within a buffer: row r, phys slot lk ^ sw(r)
    int aoff[4], boff[4];
#pragma unroll
    for (int m = 0; m < 4; ++m) {
        int r = wr * 64 + m * 16 + lr;
        aoff[m] = r * 64 + ((lk ^ ((r ^ (r >> 2)) & 3)) << 4);
    }
#pragma unroll
    for (int n = 0; n < 4; ++n) {
        int r = wc * 64 + n * 16 + lr;
        boff[n] = r * 64 + ((lk ^ ((r ^ (r >> 2)) & 3)) << 4);
    }

    // staging: 512 slot16 per matrix per buffer; 2 per thread.
    // si = j*256 + t -> row = si>>2, ps = si&3, src slot = ps ^ sw(row).
    // LDS dest si*16 B = wave-uniform + lane*16 ✓
    auto stage = [&](int ch, int buf) {
#pragma unroll
        for (int j = 0; j < 2; ++j) {
            int si = j * 256 + t;
            int row = si >> 2, ps = si & 3;
            int ss = ps ^ ((row ^ (row >> 2)) & 3);
            load_lds16(feats + (size_t)(row0 + row) * FEAT + (ch << 5) + (ss << 3),
                       &As[buf][si * 8]);
            load_lds16(Wt + (size_t)(n0 + row) * FEAT + (ch << 5) + (ss << 3),
                       &Bs[buf][si * 8]);
        }
    };

    f32x4 acc[4][4];
#pragma unroll
    for (int m = 0; m < 4; ++m)
#pragma unroll
        for (int n = 0; n < 4; ++n)
#pragma unroll
            for (int r = 0; r < 4; ++r) acc[m][n][r] = 0.0f;

    stage(0, 0);
    __syncthreads();

#define COMPUTE(BUF)                                                        \
    {                                                                       \
        bf16x8 av[4], bv[4];                                                \
        _Pragma("unroll")                                                   \
        for (int m = 0; m < 4; ++m)                                         \
            av[m] = *(const bf16x8*)((const char*)As[BUF] + aoff[m]);       \
        _Pragma("unroll")                                                   \
        for (int n = 0; n < 4; ++n)                                         \
            bv[n] = *(const bf16x8*)((const char*)Bs[BUF] + boff[n]);       \
        _Pragma("unroll")                                                   \
        for (int m = 0; m < 4; ++m)                                         \
            _Pragma("unroll")                                               \
            for (int n = 0; n < 4; ++n)                                     \
                acc[m][n] = __builtin_amdgcn_mfma_f32_16x16x32_bf16(        \
                    av[m], bv[n], acc[m][n], 0, 0, 0);                      \
    }

    for (int ch2 = 0; ch2 < 16; ++ch2) {
        {   // even chunk: compute buf0, stage next into buf1
            const int ch = ch2 * 2;
            if (ch < 31) stage(ch + 1, 1);
            COMPUTE(0);
            __syncthreads();
        }
        {   // odd chunk: compute buf1, stage next into buf0
            const int ch = ch2 * 2 + 1;
            if (ch < 31) stage(ch + 1, 0);
            COMPUTE(1);
            __syncthreads();
        }
    }
#undef COMPUTE

    // epilogue: d = sigmoid(acc + bias) -> bf16 at out row byte-cols 3072+col
#pragma unroll
    for (int m = 0; m < 4; ++m) {
#pragma unroll
        for (int n = 0; n < 4; ++n) {
            const int col = n0 + wc * 64 + n * 16 + lr;
#pragma unroll
            for (int rr = 0; rr < 4; ++rr) {
                const int row = row0 + wr * 64 + m * 16 + lk * 4 + rr;
                dout[(size_t)row * 4096 + 3072 + col] =
                    f2bf(sigmoidf(acc[m][n][rr] + bvreg[n]));
            }
        }
    }
}

// --- 5. tree expansion: 1 row per wave, register-only ----------------------
// Reads bf16 d from out byte-cols [3072:4096), writes full f32 row.
// All d loads precede the L9 stores (cols 1536..2047) in program order.
__global__ __launch_bounds__(256) void expand_tree(float* __restrict__ out) {
    const int t = threadIdx.x, l = t & 63, w = t >> 6;
    const int row = blockIdx.x * 4 + w;
    const unsigned short* dr =
        (const unsigned short*)out + (size_t)row * 4096 + 3072;
    float* orow = out + (size_t)row * OUTC;

    // ---- load ALL d into registers first ----------------------------------
    float dpath[6];
#pragma unroll
    for (int j = 0; j <= 5; ++j) {
        int idx = l >> (5 - j);
        dpath[j] = bf2f(dr[(1 << j) + (idx >> 1)]);
    }
    float d6 = bf2f(dr[64 + l]);
    unsigned int u7 = *(const unsigned int*)(dr + 128 + 2 * l);
    float d7[2] = { bf2f((unsigned short)(u7 & 0xffff)),
                    bf2f((unsigned short)(u7 >> 16)) };
    uint2 u8 = *(const uint2*)(dr + 256 + 4 * l);
    float d8[4] = { bf2f((unsigned short)(u8.x & 0xffff)),
                    bf2f((unsigned short)(u8.x >> 16)),
                    bf2f((unsigned short)(u8.y & 0xffff)),
                    bf2f((unsigned short)(u8.y >> 16)) };
    uint4 u9 = *(const uint4*)(dr + 512 + 8 * l);
    float d9[8] = { bf2f((unsigned short)(u9.x & 0xffff)),
                    bf2f((unsigned short)(u9.x >> 16)),
                    bf2f((unsigned short)(u9.y & 0xffff)),
                    bf2f((unsigned short)(u9.y >> 16)),
                    bf2f((unsigned short)(u9.z & 0xffff)),
                    bf2f((unsigned short)(u9.z >> 16)),
                    bf2f((unsigned short)(u9.w & 0xffff)),
                    bf2f((unsigned short)(u9.w >> 16)) };

    // ---- compute + store --------------------------------------------------
    float p = 1.0f;
#pragma unroll
    for (int j = 0; j <= 5; ++j) {
        int idx = l >> (5 - j);
        p *= (idx & 1) ? (1.0f - dpath[j]) : dpath[j];
        if ((l & ((1 << (5 - j)) - 1)) == 0)
            orow[(2 << j) + idx] = p;
    }
    if (l < 2) orow[l] = 1.0f;

    // L=6
    float v6[2] = { p * d6, p * (1.0f - d6) };
    *(float2*)(orow + 128 + 2 * l) = make_float2(v6[0], v6[1]);

    // L=7
    float v7[4];
#pragma unroll
    for (int e = 0; e < 4; ++e)
        v7[e] = v6[e >> 1] * ((e & 1) ? (1.0f - d7[e >> 1]) : d7[e >> 1]);
    *(float4*)(orow + 256 + 4 * l) = make_float4(v7[0], v7[1], v7[2], v7[3]);

    // L=8
    float v8[8];
#pragma unroll
    for (int e = 0; e < 8; ++e)
        v8[e] = v7[e >> 1] * ((e & 1) ? (1.0f - d8[e >> 1]) : d8[e >> 1]);
    *(float4*)(orow + 512 + 8 * l)     = make_float4(v8[0], v8[1], v8[2], v8[3]);
    *(float4*)(orow + 512 + 8 * l + 4) = make_float4(v8[4], v8[5], v8[6], v8[7]);

    // L=9 (overwrites the d region — all d already in registers)
    float v9[16];
#pragma unroll
    for (int e = 0; e < 16; ++e)
        v9[e] = v8[e >> 1] * ((e & 1) ? (1.0f - d9[e >> 1]) : d9[e >> 1]);
#pragma unroll
    for (int q = 0; q < 4; ++q)
        *(float4*)(orow + 1024 + 16 * l + 4 * q) =
            make_float4(v9[4*q], v9[4*q+1], v9[4*q+2], v9[4*q+3]);
}

// --- fallback (tiny workspace): naive fused, one row per block -------------
template <bool HAS_IDX>
__global__ __launch_bounds__(256) void fused_naive(const float* __restrict__ x,
                                                   const float* __restrict__ fm,
                                                   const float* __restrict__ W,
                                                   const float* __restrict__ bias,
                                                   const int* __restrict__ idx,
                                                   float* __restrict__ out) {
    __shared__ float fx[1024];
    __shared__ float dsm[1024];
    __shared__ float tre[2048];
    __shared__ int   idl[1024];
    const int t = threadIdx.x;
    const int row = blockIdx.x;

    if (HAS_IDX) {
        for (int k = t; k < 1024; k += 256) idl[k] = idx[k];
    } else {
        for (int k = t; k < 1024; k += 256) {
            int found = 0;
            for (int f = 0; f < 1024; ++f)
                if (fm[(size_t)f * NLEAF + k] > 0.5f) found = f;
            idl[k] = found;
        }
    }
    __syncthreads();
    const float* xr = x + (size_t)row * FEAT;
    for (int k = t; k < 1024; k += 256) fx[k] = xr[idl[k]];
    __syncthreads();

    float a0 = 0.f, a1 = 0.f, a2 = 0.f, a3 = 0.f;
    for (int k = 0; k < 1024; ++k) {
        float f = fx[k];
        const float* wrp = W + (size_t)k * NLEAF + t;
        a0 = fmaf(f, wrp[0],   a0);
        a1 = fmaf(f, wrp[256], a1);
        a2 = fmaf(f, wrp[512], a2);
        a3 = fmaf(f, wrp[768], a3);
    }
    dsm[t]       = sigmoidf(a0 + bias[t]);
    dsm[t + 256] = sigmoidf(a1 + bias[t + 256]);
    dsm[t + 512] = sigmoidf(a2 + bias[t + 512]);
    dsm[t + 768] = sigmoidf(a3 + bias[t + 768]);
    if (t < 2) tre[t] = 1.0f;
    __syncthreads();

    for (int L = 0; L < 10; ++L) {
        int n = 2 << L;
        for (int k = t; k < n; k += 256) {
            int node = (1 << L) + (k >> 1);
            float dv = dsm[node];
            tre[n + k] = tre[node] * ((k & 1) ? (1.0f - dv) : dv);
        }
        __syncthreads();
    }
    float4* orow = (float4*)(out + (size_t)row * OUTC);
    const float4* ts = (const float4*)tre;
    for (int i = t; i < 512; i += 256) orow[i] = ts[i];
}

extern "C" void kernel_launch(void* const* d_in, const int* in_sizes, int n_in,
                              void* d_out, int out_size, void* d_ws, size_t ws_size,
                              hipStream_t stream) {
    const float* x    = (const float*)d_in[0];
    const float* fm   = (const float*)d_in[1];
    const float* W    = (const float*)d_in[2];
    const float* bias = (const float*)d_in[3];
    float* out = (float*)d_out;

    const size_t IDX_B   = 4096;
    const size_t WT_B    = (size_t)NLEAF * FEAT * 2;        // 2 MiB
    const size_t FEATS_B = (size_t)BATCH * FEAT * 2;        // 32 MiB
    const size_t need = IDX_B + WT_B + FEATS_B;

    if (ws_size >= need) {
        int*   idx   = (int*)d_ws;
        short* Wt    = (short*)((char*)d_ws + IDX_B);
        short* feats = (short*)((char*)d_ws + IDX_B + WT_B);

        extract_idx<<<1024, 1024, 0, stream>>>(fm, idx);
        transpose_w<<<dim3(16, 16), 256, 0, stream>>>(W, Wt);
        gather_feats<<<BATCH * 128 / 256, 256, 0, stream>>>(x, idx, feats);
        gemm_sig_d<<<(BATCH / 128) * (NLEAF / 128), 256, 0, stream>>>(
            feats, Wt, bias, (unsigned short*)out);
        expand_tree<<<BATCH / 4, 256, 0, stream>>>(out);
    } else if (ws_size >= IDX_B) {
        int* idx = (int*)d_ws;
        extract_idx<<<1024, 1024, 0, stream>>>(fm, idx);
        fused_naive<true><<<BATCH, 256, 0, stream>>>(x, fm, W, bias, idx, out);
    } else {
        fused_naive<false><<<BATCH, 256, 0, stream>>>(x, fm, W, bias, nullptr, out);
    }
}

// Round 9
// 103.554 us; speedup vs baseline: 1.3178x; 1.1209x over previous
//
#include <hip/hip_runtime.h>

// ---------------------------------------------------------------------------
// Tree_42520176230890 (v9):
//   prep_w:   idx[l] = argmax_f fm[f][l]  +  Wt[n][k] = bf16(W[k][n])  (merged)
//   gather:   feats[r][k] = bf16(x[r][idx[k]])   (LDS-staged gather)
//   gemm:     d = sigmoid(feats @ W + b) -> bf16 into out cols[1536:2048)
//             (m97 128x128 structure, validated in v8; + XCD swizzle)
//   expand:   tree expansion, 1 row/wave, register-only
//   out: (16384, 2048) f32
// ---------------------------------------------------------------------------

typedef __bf16 bf16x8 __attribute__((ext_vector_type(8)));
typedef float  f32x4  __attribute__((ext_vector_type(4)));

#define BATCH 16384
#define NLEAF 1024
#define FEAT  1024
#define OUTC  2048

__device__ __forceinline__ unsigned short f2bf(float f) {
    union { float f; unsigned int u; } c; c.f = f;
    unsigned int u = c.u;
    u += 0x7FFFu + ((u >> 16) & 1u);   // RNE
    return (unsigned short)(u >> 16);
}

__device__ __forceinline__ float bf2f(unsigned short u) {
    union { unsigned int i; float f; } c; c.i = (unsigned int)u << 16;
    return c.f;
}

__device__ __forceinline__ void load_lds16(const void* g, void* l) {
    __builtin_amdgcn_global_load_lds(
        (const __attribute__((address_space(1))) unsigned int*)g,
        (__attribute__((address_space(3))) unsigned int*)l, 16, 0, 0);
}

__device__ __forceinline__ float sigmoidf(float z) {
    return 1.0f / (1.0f + __expf(-z));
}

// --- 1. merged: idx extract (blocks 0..1023) + W transpose (1024..1279) ----
__global__ __launch_bounds__(256) void prep_w(const float* __restrict__ fm,
                                              const float* __restrict__ W,
                                              int* __restrict__ idx,
                                              short* __restrict__ Wt) {
    __shared__ short tile[64][65];
    const int b = blockIdx.x, t = threadIdx.x;
    if (b < 1024) {
        const int f = b;
#pragma unroll
        for (int i = 0; i < 4; ++i) {
            int leaf = i * 256 + t;
            if (fm[(size_t)f * NLEAF + leaf] > 0.5f) idx[leaf] = f;
        }
    } else {
        const int tb = b - 1024;
        const int k0 = (tb >> 4) * 64, n0 = (tb & 15) * 64;
#pragma unroll
        for (int i = 0; i < 16; ++i) {
            int e = i * 256 + t;
            int kr = e >> 6, nc = e & 63;
            tile[kr][nc] = (short)f2bf(W[(size_t)(k0 + kr) * NLEAF + n0 + nc]);
        }
        __syncthreads();
#pragma unroll
        for (int i = 0; i < 16; ++i) {
            int e = i * 256 + t;
            int nr = e >> 6, kc = e & 63;
            Wt[(size_t)(n0 + nr) * FEAT + k0 + kc] = tile[kc][nr];
        }
    }
}

// --- 2. LDS-staged gather: feats[r][k] = bf16(x[r][idx[k]]) ----------------
// Block: 8 rows. Stage rows (32 KiB) + idx (4 KiB) coalesced, gather via
// ds_read_b32 (no global replay storms), store coalesced short8.
__global__ __launch_bounds__(256) void gather_feats(const float* __restrict__ x,
                                                    const int* __restrict__ idx,
                                                    short* __restrict__ feats) {
    __shared__ float xs[8][1024];
    __shared__ int   ids[1024];
    const int t = threadIdx.x;
    const int r0 = blockIdx.x * 8;

    {   // stage idx: 256 x int4
        int4 v = ((const int4*)idx)[t];
        *(int4*)&ids[t * 4] = v;
    }
#pragma unroll
    for (int j = 0; j < 8; ++j) {       // stage 8 rows: 2048 float4
        int e = j * 256 + t;
        int row = e >> 8, c4 = e & 255;
        ((float4*)xs[row])[c4] =
            ((const float4*)(x + (size_t)(r0 + row) * FEAT))[c4];
    }
    __syncthreads();

#pragma unroll
    for (int j = 0; j < 4; ++j) {       // 1024 short8 outputs
        int e = j * 256 + t;
        int row = e >> 7, kk = (e & 127) * 8;
        union { short s[8]; int4 v; } pk;
#pragma unroll
        for (int q = 0; q < 8; ++q)
            pk.s[q] = (short)f2bf(xs[row][ids[kk + q]]);
        *(int4*)(feats + (size_t)(r0 + row) * FEAT + kk) = pk.v;
    }
}

// --- 3. GEMM + sigmoid -> d (bf16) into out byte-cols [3072:4096) ----------
// m97 structure (validated v8): 128x128 tile, 256 thr (2x2 waves), BK=32 dbuf,
// global_load_lds with src-side XOR sw(r)=(r^(r>>2))&3. + bijective XCD
// swizzle: each XCD gets 16 contiguous M-rows -> A-panels L2-resident.
__global__ __launch_bounds__(256, 4) void gemm_sig_d(
        const short* __restrict__ feats, const short* __restrict__ Wt,
        const float* __restrict__ bias, unsigned short* __restrict__ dout) {
    __shared__ __align__(16) short As[2][128 * 32];
    __shared__ __align__(16) short Bs[2][128 * 32];

    const int t = threadIdx.x, l = t & 63, w = t >> 6;
    const int wr = w >> 1, wc = w & 1;
    const int lr = l & 15, lk = l >> 4;
    const int bid = blockIdx.x;
    const int swz = (bid & 7) * 128 + (bid >> 3);   // 1024 = 8 XCD x 128
    const int row0 = (swz >> 3) << 7;               // 128 M-tiles
    const int n0   = (swz & 7) << 7;                // 8 N-tiles

    float bvreg[4];
#pragma unroll
    for (int n = 0; n < 4; ++n) bvreg[n] = bias[n0 + wc * 64 + n * 16 + lr];

    int aoff[4], boff[4];
#pragma unroll
    for (int m = 0; m < 4; ++m) {
        int r = wr * 64 + m * 16 + lr;
        aoff[m] = r * 64 + ((lk ^ ((r ^ (r >> 2)) & 3)) << 4);
    }
#pragma unroll
    for (int n = 0; n < 4; ++n) {
        int r = wc * 64 + n * 16 + lr;
        boff[n] = r * 64 + ((lk ^ ((r ^ (r >> 2)) & 3)) << 4);
    }

    auto stage = [&](int ch, int buf) {
#pragma unroll
        for (int j = 0; j < 2; ++j) {
            int si = j * 256 + t;
            int row = si >> 2, ps = si & 3;
            int ss = ps ^ ((row ^ (row >> 2)) & 3);
            load_lds16(feats + (size_t)(row0 + row) * FEAT + (ch << 5) + (ss << 3),
                       &As[buf][si * 8]);
            load_lds16(Wt + (size_t)(n0 + row) * FEAT + (ch << 5) + (ss << 3),
                       &Bs[buf][si * 8]);
        }
    };

    f32x4 acc[4][4];
#pragma unroll
    for (int m = 0; m < 4; ++m)
#pragma unroll
        for (int n = 0; n < 4; ++n)
#pragma unroll
            for (int r = 0; r < 4; ++r) acc[m][n][r] = 0.0f;

    stage(0, 0);
    __syncthreads();

#define COMPUTE(BUF)                                                        \
    {                                                                       \
        bf16x8 av[4], bv[4];                                                \
        _Pragma("unroll")                                                   \
        for (int m = 0; m < 4; ++m)                                         \
            av[m] = *(const bf16x8*)((const char*)As[BUF] + aoff[m]);       \
        _Pragma("unroll")                                                   \
        for (int n = 0; n < 4; ++n)                                         \
            bv[n] = *(const bf16x8*)((const char*)Bs[BUF] + boff[n]);       \
        _Pragma("unroll")                                                   \
        for (int m = 0; m < 4; ++m)                                         \
            _Pragma("unroll")                                               \
            for (int n = 0; n < 4; ++n)                                     \
                acc[m][n] = __builtin_amdgcn_mfma_f32_16x16x32_bf16(        \
                    av[m], bv[n], acc[m][n], 0, 0, 0);                      \
    }

    for (int ch2 = 0; ch2 < 16; ++ch2) {
        {
            const int ch = ch2 * 2;
            if (ch < 31) stage(ch + 1, 1);
            COMPUTE(0);
            __syncthreads();
        }
        {
            const int ch = ch2 * 2 + 1;
            if (ch < 31) stage(ch + 1, 0);
            COMPUTE(1);
            __syncthreads();
        }
    }
#undef COMPUTE

#pragma unroll
    for (int m = 0; m < 4; ++m) {
#pragma unroll
        for (int n = 0; n < 4; ++n) {
            const int col = n0 + wc * 64 + n * 16 + lr;
#pragma unroll
            for (int rr = 0; rr < 4; ++rr) {
                const int row = row0 + wr * 64 + m * 16 + lk * 4 + rr;
                dout[(size_t)row * 4096 + 3072 + col] =
                    f2bf(sigmoidf(acc[m][n][rr] + bvreg[n]));
            }
        }
    }
}

// --- 4. tree expansion: 1 row per wave, register-only ----------------------
__global__ __launch_bounds__(256) void expand_tree(float* __restrict__ out) {
    const int t = threadIdx.x, l = t & 63, w = t >> 6;
    const int row = blockIdx.x * 4 + w;
    const unsigned short* dr =
        (const unsigned short*)out + (size_t)row * 4096 + 3072;
    float* orow = out + (size_t)row * OUTC;

    // ---- load ALL d into registers first ----------------------------------
    float dpath[6];
#pragma unroll
    for (int j = 0; j <= 5; ++j) {
        int idx = l >> (5 - j);
        dpath[j] = bf2f(dr[(1 << j) + (idx >> 1)]);
    }
    float d6 = bf2f(dr[64 + l]);
    unsigned int u7 = *(const unsigned int*)(dr + 128 + 2 * l);
    float d7[2] = { bf2f((unsigned short)(u7 & 0xffff)),
                    bf2f((unsigned short)(u7 >> 16)) };
    uint2 u8 = *(const uint2*)(dr + 256 + 4 * l);
    float d8[4] = { bf2f((unsigned short)(u8.x & 0xffff)),
                    bf2f((unsigned short)(u8.x >> 16)),
                    bf2f((unsigned short)(u8.y & 0xffff)),
                    bf2f((unsigned short)(u8.y >> 16)) };
    uint4 u9 = *(const uint4*)(dr + 512 + 8 * l);
    float d9[8] = { bf2f((unsigned short)(u9.x & 0xffff)),
                    bf2f((unsigned short)(u9.x >> 16)),
                    bf2f((unsigned short)(u9.y & 0xffff)),
                    bf2f((unsigned short)(u9.y >> 16)),
                    bf2f((unsigned short)(u9.z & 0xffff)),
                    bf2f((unsigned short)(u9.z >> 16)),
                    bf2f((unsigned short)(u9.w & 0xffff)),
                    bf2f((unsigned short)(u9.w >> 16)) };

    // ---- compute + store --------------------------------------------------
    float p = 1.0f;
#pragma unroll
    for (int j = 0; j <= 5; ++j) {
        int idx = l >> (5 - j);
        p *= (idx & 1) ? (1.0f - dpath[j]) : dpath[j];
        if ((l & ((1 << (5 - j)) - 1)) == 0)
            orow[(2 << j) + idx] = p;
    }
    if (l < 2) orow[l] = 1.0f;

    float v6[2] = { p * d6, p * (1.0f - d6) };
    *(float2*)(orow + 128 + 2 * l) = make_float2(v6[0], v6[1]);

    float v7[4];
#pragma unroll
    for (int e = 0; e < 4; ++e)
        v7[e] = v6[e >> 1] * ((e & 1) ? (1.0f - d7[e >> 1]) : d7[e >> 1]);
    *(float4*)(orow + 256 + 4 * l) = make_float4(v7[0], v7[1], v7[2], v7[3]);

    float v8[8];
#pragma unroll
    for (int e = 0; e < 8; ++e)
        v8[e] = v7[e >> 1] * ((e & 1) ? (1.0f - d8[e >> 1]) : d8[e >> 1]);
    *(float4*)(orow + 512 + 8 * l)     = make_float4(v8[0], v8[1], v8[2], v8[3]);
    *(float4*)(orow + 512 + 8 * l + 4) = make_float4(v8[4], v8[5], v8[6], v8[7]);

    float v9[16];
#pragma unroll
    for (int e = 0; e < 16; ++e)
        v9[e] = v8[e >> 1] * ((e & 1) ? (1.0f - d9[e >> 1]) : d9[e >> 1]);
#pragma unroll
    for (int q = 0; q < 4; ++q)
        *(float4*)(orow + 1024 + 16 * l + 4 * q) =
            make_float4(v9[4*q], v9[4*q+1], v9[4*q+2], v9[4*q+3]);
}

// --- fallback (tiny workspace): naive fused, one row per block -------------
template <bool HAS_IDX>
__global__ __launch_bounds__(256) void fused_naive(const float* __restrict__ x,
                                                   const float* __restrict__ fm,
                                                   const float* __restrict__ W,
                                                   const float* __restrict__ bias,
                                                   const int* __restrict__ idx,
                                                   float* __restrict__ out) {
    __shared__ float fx[1024];
    __shared__ float dsm[1024];
    __shared__ float tre[2048];
    __shared__ int   idl[1024];
    const int t = threadIdx.x;
    const int row = blockIdx.x;

    if (HAS_IDX) {
        for (int k = t; k < 1024; k += 256) idl[k] = idx[k];
    } else {
        for (int k = t; k < 1024; k += 256) {
            int found = 0;
            for (int f = 0; f < 1024; ++f)
                if (fm[(size_t)f * NLEAF + k] > 0.5f) found = f;
            idl[k] = found;
        }
    }
    __syncthreads();
    const float* xr = x + (size_t)row * FEAT;
    for (int k = t; k < 1024; k += 256) fx[k] = xr[idl[k]];
    __syncthreads();

    float a0 = 0.f, a1 = 0.f, a2 = 0.f, a3 = 0.f;
    for (int k = 0; k < 1024; ++k) {
        float f = fx[k];
        const float* wrp = W + (size_t)k * NLEAF + t;
        a0 = fmaf(f, wrp[0],   a0);
        a1 = fmaf(f, wrp[256], a1);
        a2 = fmaf(f, wrp[512], a2);
        a3 = fmaf(f, wrp[768], a3);
    }
    dsm[t]       = sigmoidf(a0 + bias[t]);
    dsm[t + 256] = sigmoidf(a1 + bias[t + 256]);
    dsm[t + 512] = sigmoidf(a2 + bias[t + 512]);
    dsm[t + 768] = sigmoidf(a3 + bias[t + 768]);
    if (t < 2) tre[t] = 1.0f;
    __syncthreads();

    for (int L = 0; L < 10; ++L) {
        int n = 2 << L;
        for (int k = t; k < n; k += 256) {
            int node = (1 << L) + (k >> 1);
            float dv = dsm[node];
            tre[n + k] = tre[node] * ((k & 1) ? (1.0f - dv) : dv);
        }
        __syncthreads();
    }
    float4* orow = (float4*)(out + (size_t)row * OUTC);
    const float4* ts = (const float4*)tre;
    for (int i = t; i < 512; i += 256) orow[i] = ts[i];
}

extern "C" void kernel_launch(void* const* d_in, const int* in_sizes, int n_in,
                              void* d_out, int out_size, void* d_ws, size_t ws_size,
                              hipStream_t stream) {
    const float* x    = (const float*)d_in[0];
    const float* fm   = (const float*)d_in[1];
    const float* W    = (const float*)d_in[2];
    const float* bias = (const float*)d_in[3];
    float* out = (float*)d_out;

    const size_t IDX_B   = 4096;
    const size_t WT_B    = (size_t)NLEAF * FEAT * 2;        // 2 MiB
    const size_t FEATS_B = (size_t)BATCH * FEAT * 2;        // 32 MiB
    const size_t need = IDX_B + WT_B + FEATS_B;

    if (ws_size >= need) {
        int*   idx   = (int*)d_ws;
        short* Wt    = (short*)((char*)d_ws + IDX_B);
        short* feats = (short*)((char*)d_ws + IDX_B + WT_B);

        prep_w<<<1280, 256, 0, stream>>>(fm, W, idx, Wt);
        gather_feats<<<BATCH / 8, 256, 0, stream>>>(x, idx, feats);
        gemm_sig_d<<<(BATCH / 128) * (NLEAF / 128), 256, 0, stream>>>(
            feats, Wt, bias, (unsigned short*)out);
        expand_tree<<<BATCH / 4, 256, 0, stream>>>(out);
    } else if (ws_size >= IDX_B) {
        int* idx = (int*)d_ws;
        prep_w<<<1280, 256, 0, stream>>>(fm, nullptr, idx, nullptr);
        fused_naive<true><<<BATCH, 256, 0, stream>>>(x, fm, W, bias, idx, out);
    } else {
        fused_naive<false><<<BATCH, 256, 0, stream>>>(x, fm, W, bias, nullptr, out);
    }
}

// Round 10
// 101.544 us; speedup vs baseline: 1.3439x; 1.0198x over previous
//
#include <hip/hip_runtime.h>

// ---------------------------------------------------------------------------
// Tree_42520176230890 (v10):
//   prep_w:   idx extract + Wt = bf16(W^T)        (merged, validated v9)
//   gather:   feats[r][k] = bf16(x[r][idx[k]])    (LDS-staged, validated v9)
//   gemm256:  d = sigmoid(feats @ W + b) -> bf16 into out cols[1536:2048)
//             NEW: 256x256 tile, 8-phase schedule (m201 template): per phase
//             {ds_read quadrant | stage half-tile -> barrier -> lgkmcnt(0)
//              -> setprio(1) 16xMFMA setprio(0) -> barrier}, vmcnt(0) once
//             per K-tile. 1 block/CU, XCD swizzle.
//   expand:   tree expansion, 1 row/wave, register-only (validated v8/v9)
// ---------------------------------------------------------------------------

typedef __bf16 bf16x8 __attribute__((ext_vector_type(8)));
typedef float  f32x4  __attribute__((ext_vector_type(4)));

#define BATCH 16384
#define NLEAF 1024
#define FEAT  1024
#define OUTC  2048

__device__ __forceinline__ unsigned short f2bf(float f) {
    union { float f; unsigned int u; } c; c.f = f;
    unsigned int u = c.u;
    u += 0x7FFFu + ((u >> 16) & 1u);   // RNE
    return (unsigned short)(u >> 16);
}

__device__ __forceinline__ float bf2f(unsigned short u) {
    union { unsigned int i; float f; } c; c.i = (unsigned int)u << 16;
    return c.f;
}

__device__ __forceinline__ void load_lds16(const void* g, void* l) {
    __builtin_amdgcn_global_load_lds(
        (const __attribute__((address_space(1))) unsigned int*)g,
        (__attribute__((address_space(3))) unsigned int*)l, 16, 0, 0);
}

__device__ __forceinline__ float sigmoidf(float z) {
    return 1.0f / (1.0f + __expf(-z));
}

// --- 1. merged: idx extract (blocks 0..1023) + W transpose (1024..1279) ----
__global__ __launch_bounds__(256) void prep_w(const float* __restrict__ fm,
                                              const float* __restrict__ W,
                                              int* __restrict__ idx,
                                              short* __restrict__ Wt) {
    __shared__ short tile[64][65];
    const int b = blockIdx.x, t = threadIdx.x;
    if (b < 1024) {
        const int f = b;
#pragma unroll
        for (int i = 0; i < 4; ++i) {
            int leaf = i * 256 + t;
            if (fm[(size_t)f * NLEAF + leaf] > 0.5f) idx[leaf] = f;
        }
    } else {
        const int tb = b - 1024;
        const int k0 = (tb >> 4) * 64, n0 = (tb & 15) * 64;
#pragma unroll
        for (int i = 0; i < 16; ++i) {
            int e = i * 256 + t;
            int kr = e >> 6, nc = e & 63;
            tile[kr][nc] = (short)f2bf(W[(size_t)(k0 + kr) * NLEAF + n0 + nc]);
        }
        __syncthreads();
#pragma unroll
        for (int i = 0; i < 16; ++i) {
            int e = i * 256 + t;
            int nr = e >> 6, kc = e & 63;
            Wt[(size_t)(n0 + nr) * FEAT + k0 + kc] = tile[kc][nr];
        }
    }
}

// --- 2. LDS-staged gather (validated v9) -----------------------------------
__global__ __launch_bounds__(256) void gather_feats(const float* __restrict__ x,
                                                    const int* __restrict__ idx,
                                                    short* __restrict__ feats) {
    __shared__ float xs[8][1024];
    __shared__ int   ids[1024];
    const int t = threadIdx.x;
    const int r0 = blockIdx.x * 8;

    {
        int4 v = ((const int4*)idx)[t];
        *(int4*)&ids[t * 4] = v;
    }
#pragma unroll
    for (int j = 0; j < 8; ++j) {
        int e = j * 256 + t;
        int row = e >> 8, c4 = e & 255;
        ((float4*)xs[row])[c4] =
            ((const float4*)(x + (size_t)(r0 + row) * FEAT))[c4];
    }
    __syncthreads();

#pragma unroll
    for (int j = 0; j < 4; ++j) {
        int e = j * 256 + t;
        int row = e >> 7, kk = (e & 127) * 8;
        union { short s[8]; int4 v; } pk;
#pragma unroll
        for (int q = 0; q < 8; ++q)
            pk.s[q] = (short)f2bf(xs[row][ids[kk + q]]);
        *(int4*)(feats + (size_t)(r0 + row) * FEAT + kk) = pk.v;
    }
}

// --- 3. GEMM 256x256, 8-phase -> d (bf16) into out byte-cols [3072:4096) ---
// 512 thr = 8 waves (2M x 4N), wave-tile 128x64, acc[8][4] f32x4.
// LDS 128 KiB: A[2buf][2half][128r][64k] bf16 (64K) + B same (64K).
// XOR slot swizzle: phys slot = (kh*4+lk) ^ (row&7), applied on stage SOURCE.
// Per K-tile (BK=64): 4 phases; phase P computes C-quadrant (qm=P>>1, qn=P&1)
// = 16 MFMA, stages half-tile P of tile t+1. vmcnt(0) once per tile.

// stage half-tile P of K-tile TT into buffer BUFN (P: 0=A/h0 1=A/h1 2=B/h0 3=B/h1)
#define STAGEH(P, TT, BUFN)                                                   \
    {                                                                         \
        constexpr int hh = (P) & 1;                                           \
        _Pragma("unroll")                                                     \
        for (int j = 0; j < 2; ++j) {                                         \
            const int r = j * 64 + r8;                                        \
            if ((P) < 2) {                                                    \
                load_lds16(feats + (size_t)(row0 + hh * 128 + r) * FEAT       \
                               + ((TT) << 6) + (ss << 3),                     \
                           smem + (BUFN) * 32768 + hh * 16384                 \
                               + (j * 512 + tid) * 16);                       \
            } else {                                                          \
                load_lds16(Wt + (size_t)(n0 + hh * 128 + r) * FEAT            \
                               + ((TT) << 6) + (ss << 3),                     \
                           smem + 65536 + (BUFN) * 32768 + hh * 16384         \
                               + (j * 512 + tid) * 16);                       \
            }                                                                 \
        }                                                                     \
    }

#define GPHASE(P, DO_STAGE, DO_WAITV)                                         \
    {                                                                         \
        constexpr int qm = (P) >> 1, qn = (P) & 1;                            \
        bf16x8 av[4][2], bv[2][2];                                            \
        _Pragma("unroll")                                                     \
        for (int mm = 0; mm < 4; ++mm)                                        \
            _Pragma("unroll")                                                 \
            for (int kh = 0; kh < 2; ++kh)                                    \
                av[mm][kh] = *(const bf16x8*)(smem + bufA                     \
                               + aRow[qm * 4 + mm] + slotoff[kh]);            \
        _Pragma("unroll")                                                     \
        for (int nn = 0; nn < 2; ++nn)                                        \
            _Pragma("unroll")                                                 \
            for (int kh = 0; kh < 2; ++kh)                                    \
                bv[nn][kh] = *(const bf16x8*)(smem + bufA                     \
                               + bRow[qn * 2 + nn] + slotoff[kh]);            \
        if (DO_STAGE) STAGEH(P, t + 1, bufN);                                 \
        __builtin_amdgcn_s_barrier();                                         \
        asm volatile("s_waitcnt lgkmcnt(0)" ::: "memory");                    \
        __builtin_amdgcn_sched_barrier(0);                                    \
        __builtin_amdgcn_s_setprio(1);                                        \
        _Pragma("unroll")                                                     \
        for (int mm = 0; mm < 4; ++mm)                                        \
            _Pragma("unroll")                                                 \
            for (int nn = 0; nn < 2; ++nn)                                    \
                _Pragma("unroll")                                             \
                for (int kh = 0; kh < 2; ++kh)                                \
                    acc[qm * 4 + mm][qn * 2 + nn] =                           \
                        __builtin_amdgcn_mfma_f32_16x16x32_bf16(              \
                            av[mm][kh], bv[nn][kh],                           \
                            acc[qm * 4 + mm][qn * 2 + nn], 0, 0, 0);          \
        __builtin_amdgcn_s_setprio(0);                                        \
        if (DO_WAITV) { asm volatile("s_waitcnt vmcnt(0)" ::: "memory"); }    \
        __builtin_amdgcn_s_barrier();                                         \
    }

__global__ __launch_bounds__(512, 2) void gemm256_sig_d(
        const short* __restrict__ feats, const short* __restrict__ Wt,
        const float* __restrict__ bias, unsigned short* __restrict__ dout) {
    __shared__ __align__(16) char smem_[131072];
    char* smem = smem_;

    const int tid = threadIdx.x, l = tid & 63, w = tid >> 6;
    const int wr = w >> 2, wc = w & 3;          // 2M x 4N wave grid
    const int lr = l & 15, lk = l >> 4;
    const int bid = blockIdx.x;
    const int swz = (bid & 7) * 32 + (bid >> 3);   // 256 = 8 XCD x 32
    const int row0 = (swz >> 2) << 8;              // 64 M-tiles
    const int n0   = (swz & 3) << 8;               // 4 N-tiles

    // staging constants: si = j*512 + tid -> row = j*64 + r8, phys slot ss0
    const int r8 = tid >> 3;
    const int ss = (tid & 7) ^ (r8 & 7);          // source k-slot (inverse swz)

    // ds_read byte offsets (within A region / B uses +65536 baked into bRow)
    int aRow[8], bRow[4], slotoff[2];
#pragma unroll
    for (int m = 0; m < 8; ++m)
        aRow[m] = wr * 16384 + (m * 16 + lr) * 128;
#pragma unroll
    for (int n = 0; n < 4; ++n)
        bRow[n] = 65536 + (wc >> 1) * 16384 + ((wc & 1) * 64 + n * 16 + lr) * 128;
#pragma unroll
    for (int kh = 0; kh < 2; ++kh)
        slotoff[kh] = ((kh * 4 + lk) ^ (lr & 7)) * 16;

    float bvreg[4];
#pragma unroll
    for (int n = 0; n < 4; ++n)
        bvreg[n] = bias[n0 + wc * 64 + n * 16 + lr];

    f32x4 acc[8][4];
#pragma unroll
    for (int m = 0; m < 8; ++m)
#pragma unroll
        for (int n = 0; n < 4; ++n)
#pragma unroll
            for (int r = 0; r < 4; ++r) acc[m][n][r] = 0.0f;

    // prologue: stage all 4 half-tiles of K-tile 0 into buf 0
    STAGEH(0, 0, 0);
    STAGEH(1, 0, 0);
    STAGEH(2, 0, 0);
    STAGEH(3, 0, 0);
    asm volatile("s_waitcnt vmcnt(0)" ::: "memory");
    __builtin_amdgcn_s_barrier();

    for (int t = 0; t < 16; ++t) {
        const int bufA = (t & 1) * 32768;
        const int bufN = (t & 1) ^ 1;
        const bool st = (t < 15);
        GPHASE(0, st, false);
        GPHASE(1, st, false);
        GPHASE(2, st, false);
        GPHASE(3, st, st);
    }

    // epilogue: d = sigmoid(acc + bias) -> bf16 at out row byte-cols 3072+col
#pragma unroll
    for (int m = 0; m < 8; ++m) {
#pragma unroll
        for (int n = 0; n < 4; ++n) {
            const int col = n0 + wc * 64 + n * 16 + lr;
#pragma unroll
            for (int rr = 0; rr < 4; ++rr) {
                const int row = row0 + wr * 128 + m * 16 + lk * 4 + rr;
                dout[(size_t)row * 4096 + 3072 + col] =
                    f2bf(sigmoidf(acc[m][n][rr] + bvreg[n]));
            }
        }
    }
}

// --- 4. tree expansion: 1 row per wave, register-only (validated) ----------
__global__ __launch_bounds__(256) void expand_tree(float* __restrict__ out) {
    const int t = threadIdx.x, l = t & 63, w = t >> 6;
    const int row = blockIdx.x * 4 + w;
    const unsigned short* dr =
        (const unsigned short*)out + (size_t)row * 4096 + 3072;
    float* orow = out + (size_t)row * OUTC;

    float dpath[6];
#pragma unroll
    for (int j = 0; j <= 5; ++j) {
        int idx = l >> (5 - j);
        dpath[j] = bf2f(dr[(1 << j) + (idx >> 1)]);
    }
    float d6 = bf2f(dr[64 + l]);
    unsigned int u7 = *(const unsigned int*)(dr + 128 + 2 * l);
    float d7[2] = { bf2f((unsigned short)(u7 & 0xffff)),
                    bf2f((unsigned short)(u7 >> 16)) };
    uint2 u8 = *(const uint2*)(dr + 256 + 4 * l);
    float d8[4] = { bf2f((unsigned short)(u8.x & 0xffff)),
                    bf2f((unsigned short)(u8.x >> 16)),
                    bf2f((unsigned short)(u8.y & 0xffff)),
                    bf2f((unsigned short)(u8.y >> 16)) };
    uint4 u9 = *(const uint4*)(dr + 512 + 8 * l);
    float d9[8] = { bf2f((unsigned short)(u9.x & 0xffff)),
                    bf2f((unsigned short)(u9.x >> 16)),
                    bf2f((unsigned short)(u9.y & 0xffff)),
                    bf2f((unsigned short)(u9.y >> 16)),
                    bf2f((unsigned short)(u9.z & 0xffff)),
                    bf2f((unsigned short)(u9.z >> 16)),
                    bf2f((unsigned short)(u9.w & 0xffff)),
                    bf2f((unsigned short)(u9.w >> 16)) };

    float p = 1.0f;
#pragma unroll
    for (int j = 0; j <= 5; ++j) {
        int idx = l >> (5 - j);
        p *= (idx & 1) ? (1.0f - dpath[j]) : dpath[j];
        if ((l & ((1 << (5 - j)) - 1)) == 0)
            orow[(2 << j) + idx] = p;
    }
    if (l < 2) orow[l] = 1.0f;

    float v6[2] = { p * d6, p * (1.0f - d6) };
    *(float2*)(orow + 128 + 2 * l) = make_float2(v6[0], v6[1]);

    float v7[4];
#pragma unroll
    for (int e = 0; e < 4; ++e)
        v7[e] = v6[e >> 1] * ((e & 1) ? (1.0f - d7[e >> 1]) : d7[e >> 1]);
    *(float4*)(orow + 256 + 4 * l) = make_float4(v7[0], v7[1], v7[2], v7[3]);

    float v8[8];
#pragma unroll
    for (int e = 0; e < 8; ++e)
        v8[e] = v7[e >> 1] * ((e & 1) ? (1.0f - d8[e >> 1]) : d8[e >> 1]);
    *(float4*)(orow + 512 + 8 * l)     = make_float4(v8[0], v8[1], v8[2], v8[3]);
    *(float4*)(orow + 512 + 8 * l + 4) = make_float4(v8[4], v8[5], v8[6], v8[7]);

    float v9[16];
#pragma unroll
    for (int e = 0; e < 16; ++e)
        v9[e] = v8[e >> 1] * ((e & 1) ? (1.0f - d9[e >> 1]) : d9[e >> 1]);
#pragma unroll
    for (int q = 0; q < 4; ++q)
        *(float4*)(orow + 1024 + 16 * l + 4 * q) =
            make_float4(v9[4*q], v9[4*q+1], v9[4*q+2], v9[4*q+3]);
}

// --- fallback (tiny workspace): naive fused, one row per block -------------
template <bool HAS_IDX>
__global__ __launch_bounds__(256) void fused_naive(const float* __restrict__ x,
                                                   const float* __restrict__ fm,
                                                   const float* __restrict__ W,
                                                   const float* __restrict__ bias,
                                                   const int* __restrict__ idx,
                                                   float* __restrict__ out) {
    __shared__ float fx[1024];
    __shared__ float dsm[1024];
    __shared__ float tre[2048];
    __shared__ int   idl[1024];
    const int t = threadIdx.x;
    const int row = blockIdx.x;

    if (HAS_IDX) {
        for (int k = t; k < 1024; k += 256) idl[k] = idx[k];
    } else {
        for (int k = t; k < 1024; k += 256) {
            int found = 0;
            for (int f = 0; f < 1024; ++f)
                if (fm[(size_t)f * NLEAF + k] > 0.5f) found = f;
            idl[k] = found;
        }
    }
    __syncthreads();
    const float* xr = x + (size_t)row * FEAT;
    for (int k = t; k < 1024; k += 256) fx[k] = xr[idl[k]];
    __syncthreads();

    float a0 = 0.f, a1 = 0.f, a2 = 0.f, a3 = 0.f;
    for (int k = 0; k < 1024; ++k) {
        float f = fx[k];
        const float* wrp = W + (size_t)k * NLEAF + t;
        a0 = fmaf(f, wrp[0],   a0);
        a1 = fmaf(f, wrp[256], a1);
        a2 = fmaf(f, wrp[512], a2);
        a3 = fmaf(f, wrp[768], a3);
    }
    dsm[t]       = sigmoidf(a0 + bias[t]);
    dsm[t + 256] = sigmoidf(a1 + bias[t + 256]);
    dsm[t + 512] = sigmoidf(a2 + bias[t + 512]);
    dsm[t + 768] = sigmoidf(a3 + bias[t + 768]);
    if (t < 2) tre[t] = 1.0f;
    __syncthreads();

    for (int L = 0; L < 10; ++L) {
        int n = 2 << L;
        for (int k = t; k < n; k += 256) {
            int node = (1 << L) + (k >> 1);
            float dv = dsm[node];
            tre[n + k] = tre[node] * ((k & 1) ? (1.0f - dv) : dv);
        }
        __syncthreads();
    }
    float4* orow = (float4*)(out + (size_t)row * OUTC);
    const float4* ts = (const float4*)tre;
    for (int i = t; i < 512; i += 256) orow[i] = ts[i];
}

extern "C" void kernel_launch(void* const* d_in, const int* in_sizes, int n_in,
                              void* d_out, int out_size, void* d_ws, size_t ws_size,
                              hipStream_t stream) {
    const float* x    = (const float*)d_in[0];
    const float* fm   = (const float*)d_in[1];
    const float* W    = (const float*)d_in[2];
    const float* bias = (const float*)d_in[3];
    float* out = (float*)d_out;

    const size_t IDX_B   = 4096;
    const size_t WT_B    = (size_t)NLEAF * FEAT * 2;        // 2 MiB
    const size_t FEATS_B = (size_t)BATCH * FEAT * 2;        // 32 MiB
    const size_t need = IDX_B + WT_B + FEATS_B;

    if (ws_size >= need) {
        int*   idx   = (int*)d_ws;
        short* Wt    = (short*)((char*)d_ws + IDX_B);
        short* feats = (short*)((char*)d_ws + IDX_B + WT_B);

        prep_w<<<1280, 256, 0, stream>>>(fm, W, idx, Wt);
        gather_feats<<<BATCH / 8, 256, 0, stream>>>(x, idx, feats);
        gemm256_sig_d<<<(BATCH / 256) * (NLEAF / 256), 512, 0, stream>>>(
            feats, Wt, bias, (unsigned short*)out);
        expand_tree<<<BATCH / 4, 256, 0, stream>>>(out);
    } else if (ws_size >= IDX_B) {
        int* idx = (int*)d_ws;
        prep_w<<<1280, 256, 0, stream>>>(fm, nullptr, idx, nullptr);
        fused_naive<true><<<BATCH, 256, 0, stream>>>(x, fm, W, bias, idx, out);
    } else {
        fused_naive<false><<<BATCH, 256, 0, stream>>>(x, fm, W, bias, nullptr, out);
    }
}

// Round 11
// 97.535 us; speedup vs baseline: 1.3991x; 1.0411x over previous
//
#include <hip/hip_runtime.h>

// ---------------------------------------------------------------------------
// Tree_42520176230890 (v11):
//   prep_w:   idx extract + Wt = bf16(W^T)        (merged, validated v9)
//   gather:   feats[r][k] = bf16(x[r][idx[k]])    (LDS-staged, validated v9)
//   gemm256:  d = sigmoid(feats @ W + b) -> bf16 into out cols[1536:2048)
//             256x256 tile, 8 waves; K-halved LDS (A/B [buf][kh][256][32k])
//             -> per-phase reads confined to one k-half -> COUNTED vmcnt(4)
//             at 2 of 4 phase boundaries (T4); loads never drained mid-loop.
//   expand:   tree expansion, 1 row/wave, register-only (validated v8/v9)
// ---------------------------------------------------------------------------

typedef __bf16 bf16x8 __attribute__((ext_vector_type(8)));
typedef float  f32x4  __attribute__((ext_vector_type(4)));

#define BATCH 16384
#define NLEAF 1024
#define FEAT  1024
#define OUTC  2048

__device__ __forceinline__ unsigned short f2bf(float f) {
    union { float f; unsigned int u; } c; c.f = f;
    unsigned int u = c.u;
    u += 0x7FFFu + ((u >> 16) & 1u);   // RNE
    return (unsigned short)(u >> 16);
}

__device__ __forceinline__ float bf2f(unsigned short u) {
    union { unsigned int i; float f; } c; c.i = (unsigned int)u << 16;
    return c.f;
}

__device__ __forceinline__ void load_lds16(const void* g, void* l) {
    __builtin_amdgcn_global_load_lds(
        (const __attribute__((address_space(1))) unsigned int*)g,
        (__attribute__((address_space(3))) unsigned int*)l, 16, 0, 0);
}

__device__ __forceinline__ float sigmoidf(float z) {
    return 1.0f / (1.0f + __expf(-z));
}

// --- 1. merged: idx extract (blocks 0..1023) + W transpose (1024..1279) ----
__global__ __launch_bounds__(256) void prep_w(const float* __restrict__ fm,
                                              const float* __restrict__ W,
                                              int* __restrict__ idx,
                                              short* __restrict__ Wt) {
    __shared__ short tile[64][65];
    const int b = blockIdx.x, t = threadIdx.x;
    if (b < 1024) {
        const int f = b;
#pragma unroll
        for (int i = 0; i < 4; ++i) {
            int leaf = i * 256 + t;
            if (fm[(size_t)f * NLEAF + leaf] > 0.5f) idx[leaf] = f;
        }
    } else {
        const int tb = b - 1024;
        const int k0 = (tb >> 4) * 64, n0 = (tb & 15) * 64;
#pragma unroll
        for (int i = 0; i < 16; ++i) {
            int e = i * 256 + t;
            int kr = e >> 6, nc = e & 63;
            tile[kr][nc] = (short)f2bf(W[(size_t)(k0 + kr) * NLEAF + n0 + nc]);
        }
        __syncthreads();
#pragma unroll
        for (int i = 0; i < 16; ++i) {
            int e = i * 256 + t;
            int nr = e >> 6, kc = e & 63;
            Wt[(size_t)(n0 + nr) * FEAT + k0 + kc] = tile[kc][nr];
        }
    }
}

// --- 2. LDS-staged gather (validated v9) -----------------------------------
__global__ __launch_bounds__(256) void gather_feats(const float* __restrict__ x,
                                                    const int* __restrict__ idx,
                                                    short* __restrict__ feats) {
    __shared__ float xs[8][1024];
    __shared__ int   ids[1024];
    const int t = threadIdx.x;
    const int r0 = blockIdx.x * 8;

    {
        int4 v = ((const int4*)idx)[t];
        *(int4*)&ids[t * 4] = v;
    }
#pragma unroll
    for (int j = 0; j < 8; ++j) {
        int e = j * 256 + t;
        int row = e >> 8, c4 = e & 255;
        ((float4*)xs[row])[c4] =
            ((const float4*)(x + (size_t)(r0 + row) * FEAT))[c4];
    }
    __syncthreads();

#pragma unroll
    for (int j = 0; j < 4; ++j) {
        int e = j * 256 + t;
        int row = e >> 7, kk = (e & 127) * 8;
        union { short s[8]; int4 v; } pk;
#pragma unroll
        for (int q = 0; q < 8; ++q)
            pk.s[q] = (short)f2bf(xs[row][ids[kk + q]]);
        *(int4*)(feats + (size_t)(r0 + row) * FEAT + kk) = pk.v;
    }
}

// --- 3. GEMM 256x256, counted-vmcnt 8-phase --------------------------------
// 512 thr = 8 waves (2M x 4N), wave-tile 128x64, acc[8][4] f32x4.
// LDS 128 KiB: A[2buf][2kh][256r][4slot16] (64K) + B same (64K at +65536).
// Swizzle: phys slot = slot ^ ((row>>1)&3) (2-way, free), applied src-side.
// Per K-tile: 4 phases (qm,kh) = 16 MFMA each; stage order A0,B0,A1,B1 of
// tile t+1; vmcnt(4) before closing barrier of phases 1 & 3 ONLY (T4).

// stage half-tile (MAT: 0=A 1=B, KH) of K-tile TT into buffer BUFN
#define STAGEH(MAT, KH, TT, BUFN)                                             \
    {                                                                         \
        _Pragma("unroll")                                                     \
        for (int j = 0; j < 2; ++j) {                                         \
            const int slotidx = j * 512 + tid;                                \
            const int srow = slotidx >> 2;                                    \
            const short* srcb = (MAT) ? (Wt + (size_t)(n0 + srow) * FEAT)     \
                                      : (feats + (size_t)(row0 + srow) * FEAT);\
            load_lds16(srcb + ((TT) << 6) + ((KH) << 5) + (ssrc << 3),        \
                       smem + (MAT) * 65536 + (BUFN) * 32768                  \
                            + (KH) * 16384 + slotidx * 16);                   \
        }                                                                     \
    }

// WAITV: 0 = none, 1 = vmcnt(4), 2 = vmcnt(0)
#define GPHASE(QM, KH, DO_STAGE, SMAT, SKH, WAITV)                            \
    {                                                                         \
        bf16x8 av[4];                                                         \
        _Pragma("unroll")                                                     \
        for (int mm = 0; mm < 4; ++mm)                                        \
            av[mm] = *(const bf16x8*)(smem + bufA + (KH) * 16384              \
                                      + aRow[(QM) * 4 + mm]);                 \
        if ((QM) == 0) {                                                      \
            _Pragma("unroll")                                                 \
            for (int nn = 0; nn < 4; ++nn)                                    \
                bvk[nn] = *(const bf16x8*)(smem + bufA + (KH) * 16384         \
                                           + bRow[nn]);                       \
        }                                                                     \
        if (DO_STAGE) STAGEH(SMAT, SKH, t + 1, bufN);                         \
        __builtin_amdgcn_s_barrier();                                         \
        asm volatile("s_waitcnt lgkmcnt(0)" ::: "memory");                    \
        __builtin_amdgcn_sched_barrier(0);                                    \
        __builtin_amdgcn_s_setprio(1);                                        \
        _Pragma("unroll")                                                     \
        for (int mm = 0; mm < 4; ++mm)                                        \
            _Pragma("unroll")                                                 \
            for (int nn = 0; nn < 4; ++nn)                                    \
                acc[(QM) * 4 + mm][nn] =                                      \
                    __builtin_amdgcn_mfma_f32_16x16x32_bf16(                  \
                        av[mm], bvk[nn], acc[(QM) * 4 + mm][nn], 0, 0, 0);    \
        __builtin_amdgcn_s_setprio(0);                                        \
        if ((WAITV) == 1) { asm volatile("s_waitcnt vmcnt(4)" ::: "memory"); }\
        if ((WAITV) == 2) { asm volatile("s_waitcnt vmcnt(0)" ::: "memory"); }\
        __builtin_amdgcn_s_barrier();                                         \
    }

__global__ __launch_bounds__(512, 2) void gemm256_sig_d(
        const short* __restrict__ feats, const short* __restrict__ Wt,
        const float* __restrict__ bias, unsigned short* __restrict__ dout) {
    __shared__ __align__(16) char smem_[131072];
    char* smem = smem_;

    const int tid = threadIdx.x, l = tid & 63, w = tid >> 6;
    const int wr = w >> 2, wc = w & 3;             // 2M x 4N wave grid
    const int lr = l & 15, lk = l >> 4;            // lk in 0..3 (4 slot16/kh)
    const int bid = blockIdx.x;
    const int swz = (bid & 7) * 32 + (bid >> 3);   // 256 = 8 XCD x 32
    const int row0 = (swz >> 2) << 8;              // 64 M-tiles
    const int n0   = (swz & 3) << 8;               // 4 N-tiles

    // staging source slot (inverse swizzle), j-invariant
    const int ssrc = (tid & 3) ^ ((tid >> 3) & 3);

    // ds_read byte offsets: row*64 + physslot*16, physslot = lk ^ ((lr>>1)&3)
    const int slotoff = (lk ^ ((lr >> 1) & 3)) << 4;
    int aRow[8], bRow[4];
#pragma unroll
    for (int m = 0; m < 8; ++m)
        aRow[m] = (wr * 128 + m * 16 + lr) * 64 + slotoff;
#pragma unroll
    for (int n = 0; n < 4; ++n)
        bRow[n] = 65536 + (wc * 64 + n * 16 + lr) * 64 + slotoff;

    float bvreg[4];
#pragma unroll
    for (int n = 0; n < 4; ++n)
        bvreg[n] = bias[n0 + wc * 64 + n * 16 + lr];

    f32x4 acc[8][4];
#pragma unroll
    for (int m = 0; m < 8; ++m)
#pragma unroll
        for (int n = 0; n < 4; ++n)
#pragma unroll
            for (int r = 0; r < 4; ++r) acc[m][n][r] = 0.0f;

    // prologue: stage tile 0 (buf 0) in order A0,B0,A1,B1; counted wait
    {
        const int t = -1, bufN = 0;    // STAGEH uses t+1 = 0
        STAGEH(0, 0, t + 1, bufN);
        STAGEH(1, 0, t + 1, bufN);
        STAGEH(0, 1, t + 1, bufN);
        STAGEH(1, 1, t + 1, bufN);
    }
    asm volatile("s_waitcnt vmcnt(4)" ::: "memory");   // A0,B0 landed
    __builtin_amdgcn_s_barrier();

    bf16x8 bvk[4];
    for (int t = 0; t < 15; ++t) {
        const int bufA = (t & 1) * 32768;
        const int bufN = (t & 1) ^ 1;
        GPHASE(0, 0, true, 0, 0, 0);   // stage A-kh0(t+1)
        GPHASE(1, 0, true, 1, 0, 1);   // stage B-kh0(t+1); vmcnt(4)
        GPHASE(0, 1, true, 0, 1, 0);   // stage A-kh1(t+1)
        GPHASE(1, 1, true, 1, 1, 1);   // stage B-kh1(t+1); vmcnt(4)
    }
    {   // tail tile 15: no stages; drain kh1 halves at phase-1 end
        const int t = 15;
        const int bufA = 32768, bufN = 0;
        (void)bufN;
        GPHASE(0, 0, false, 0, 0, 0);
        GPHASE(1, 0, false, 1, 0, 2);  // vmcnt(0): kh1 halves landed
        GPHASE(0, 1, false, 0, 1, 0);
        GPHASE(1, 1, false, 1, 1, 0);
    }

    // epilogue: d = sigmoid(acc + bias) -> bf16 at out row byte-cols 3072+col
#pragma unroll
    for (int m = 0; m < 8; ++m) {
#pragma unroll
        for (int n = 0; n < 4; ++n) {
            const int col = n0 + wc * 64 + n * 16 + lr;
#pragma unroll
            for (int rr = 0; rr < 4; ++rr) {
                const int row = row0 + wr * 128 + m * 16 + lk * 4 + rr;
                dout[(size_t)row * 4096 + 3072 + col] =
                    f2bf(sigmoidf(acc[m][n][rr] + bvreg[n]));
            }
        }
    }
}

// --- 4. tree expansion: 1 row per wave, register-only (validated) ----------
__global__ __launch_bounds__(256) void expand_tree(float* __restrict__ out) {
    const int t = threadIdx.x, l = t & 63, w = t >> 6;
    const int row = blockIdx.x * 4 + w;
    const unsigned short* dr =
        (const unsigned short*)out + (size_t)row * 4096 + 3072;
    float* orow = out + (size_t)row * OUTC;

    float dpath[6];
#pragma unroll
    for (int j = 0; j <= 5; ++j) {
        int idx = l >> (5 - j);
        dpath[j] = bf2f(dr[(1 << j) + (idx >> 1)]);
    }
    float d6 = bf2f(dr[64 + l]);
    unsigned int u7 = *(const unsigned int*)(dr + 128 + 2 * l);
    float d7[2] = { bf2f((unsigned short)(u7 & 0xffff)),
                    bf2f((unsigned short)(u7 >> 16)) };
    uint2 u8 = *(const uint2*)(dr + 256 + 4 * l);
    float d8[4] = { bf2f((unsigned short)(u8.x & 0xffff)),
                    bf2f((unsigned short)(u8.x >> 16)),
                    bf2f((unsigned short)(u8.y & 0xffff)),
                    bf2f((unsigned short)(u8.y >> 16)) };
    uint4 u9 = *(const uint4*)(dr + 512 + 8 * l);
    float d9[8] = { bf2f((unsigned short)(u9.x & 0xffff)),
                    bf2f((unsigned short)(u9.x >> 16)),
                    bf2f((unsigned short)(u9.y & 0xffff)),
                    bf2f((unsigned short)(u9.y >> 16)),
                    bf2f((unsigned short)(u9.z & 0xffff)),
                    bf2f((unsigned short)(u9.z >> 16)),
                    bf2f((unsigned short)(u9.w & 0xffff)),
                    bf2f((unsigned short)(u9.w >> 16)) };

    float p = 1.0f;
#pragma unroll
    for (int j = 0; j <= 5; ++j) {
        int idx = l >> (5 - j);
        p *= (idx & 1) ? (1.0f - dpath[j]) : dpath[j];
        if ((l & ((1 << (5 - j)) - 1)) == 0)
            orow[(2 << j) + idx] = p;
    }
    if (l < 2) orow[l] = 1.0f;

    float v6[2] = { p * d6, p * (1.0f - d6) };
    *(float2*)(orow + 128 + 2 * l) = make_float2(v6[0], v6[1]);

    float v7[4];
#pragma unroll
    for (int e = 0; e < 4; ++e)
        v7[e] = v6[e >> 1] * ((e & 1) ? (1.0f - d7[e >> 1]) : d7[e >> 1]);
    *(float4*)(orow + 256 + 4 * l) = make_float4(v7[0], v7[1], v7[2], v7[3]);

    float v8[8];
#pragma unroll
    for (int e = 0; e < 8; ++e)
        v8[e] = v7[e >> 1] * ((e & 1) ? (1.0f - d8[e >> 1]) : d8[e >> 1]);
    *(float4*)(orow + 512 + 8 * l)     = make_float4(v8[0], v8[1], v8[2], v8[3]);
    *(float4*)(orow + 512 + 8 * l + 4) = make_float4(v8[4], v8[5], v8[6], v8[7]);

    float v9[16];
#pragma unroll
    for (int e = 0; e < 16; ++e)
        v9[e] = v8[e >> 1] * ((e & 1) ? (1.0f - d9[e >> 1]) : d9[e >> 1]);
#pragma unroll
    for (int q = 0; q < 4; ++q)
        *(float4*)(orow + 1024 + 16 * l + 4 * q) =
            make_float4(v9[4*q], v9[4*q+1], v9[4*q+2], v9[4*q+3]);
}

// --- fallback (tiny workspace): naive fused, one row per block -------------
template <bool HAS_IDX>
__global__ __launch_bounds__(256) void fused_naive(const float* __restrict__ x,
                                                   const float* __restrict__ fm,
                                                   const float* __restrict__ W,
                                                   const float* __restrict__ bias,
                                                   const int* __restrict__ idx,
                                                   float* __restrict__ out) {
    __shared__ float fx[1024];
    __shared__ float dsm[1024];
    __shared__ float tre[2048];
    __shared__ int   idl[1024];
    const int t = threadIdx.x;
    const int row = blockIdx.x;

    if (HAS_IDX) {
        for (int k = t; k < 1024; k += 256) idl[k] = idx[k];
    } else {
        for (int k = t; k < 1024; k += 256) {
            int found = 0;
            for (int f = 0; f < 1024; ++f)
                if (fm[(size_t)f * NLEAF + k] > 0.5f) found = f;
            idl[k] = found;
        }
    }
    __syncthreads();
    const float* xr = x + (size_t)row * FEAT;
    for (int k = t; k < 1024; k += 256) fx[k] = xr[idl[k]];
    __syncthreads();

    float a0 = 0.f, a1 = 0.f, a2 = 0.f, a3 = 0.f;
    for (int k = 0; k < 1024; ++k) {
        float f = fx[k];
        const float* wrp = W + (size_t)k * NLEAF + t;
        a0 = fmaf(f, wrp[0],   a0);
        a1 = fmaf(f, wrp[256], a1);
        a2 = fmaf(f, wrp[512], a2);
        a3 = fmaf(f, wrp[768], a3);
    }
    dsm[t]       = sigmoidf(a0 + bias[t]);
    dsm[t + 256] = sigmoidf(a1 + bias[t + 256]);
    dsm[t + 512] = sigmoidf(a2 + bias[t + 512]);
    dsm[t + 768] = sigmoidf(a3 + bias[t + 768]);
    if (t < 2) tre[t] = 1.0f;
    __syncthreads();

    for (int L = 0; L < 10; ++L) {
        int n = 2 << L;
        for (int k = t; k < n; k += 256) {
            int node = (1 << L) + (k >> 1);
            float dv = dsm[node];
            tre[n + k] = tre[node] * ((k & 1) ? (1.0f - dv) : dv);
        }
        __syncthreads();
    }
    float4* orow = (float4*)(out + (size_t)row * OUTC);
    const float4* ts = (const float4*)tre;
    for (int i = t; i < 512; i += 256) orow[i] = ts[i];
}

extern "C" void kernel_launch(void* const* d_in, const int* in_sizes, int n_in,
                              void* d_out, int out_size, void* d_ws, size_t ws_size,
                              hipStream_t stream) {
    const float* x    = (const float*)d_in[0];
    const float* fm   = (const float*)d_in[1];
    const float* W    = (const float*)d_in[2];
    const float* bias = (const float*)d_in[3];
    float* out = (float*)d_out;

    const size_t IDX_B   = 4096;
    const size_t WT_B    = (size_t)NLEAF * FEAT * 2;        // 2 MiB
    const size_t FEATS_B = (size_t)BATCH * FEAT * 2;        // 32 MiB
    const size_t need = IDX_B + WT_B + FEATS_B;

    if (ws_size >= need) {
        int*   idx   = (int*)d_ws;
        short* Wt    = (short*)((char*)d_ws + IDX_B);
        short* feats = (short*)((char*)d_ws + IDX_B + WT_B);

        prep_w<<<1280, 256, 0, stream>>>(fm, W, idx, Wt);
        gather_feats<<<BATCH / 8, 256, 0, stream>>>(x, idx, feats);
        gemm256_sig_d<<<(BATCH / 256) * (NLEAF / 256), 512, 0, stream>>>(
            feats, Wt, bias, (unsigned short*)out);
        expand_tree<<<BATCH / 4, 256, 0, stream>>>(out);
    } else if (ws_size >= IDX_B) {
        int* idx = (int*)d_ws;
        prep_w<<<1280, 256, 0, stream>>>(fm, nullptr, idx, nullptr);
        fused_naive<true><<<BATCH, 256, 0, stream>>>(x, fm, W, bias, idx, out);
    } else {
        fused_naive<false><<<BATCH, 256, 0, stream>>>(x, fm, W, bias, nullptr, out);
    }
}